// Round 1
// baseline (519.132 us; speedup 1.0000x reference)
//
#include <hip/hip_runtime.h>

typedef __attribute__((ext_vector_type(8))) short short8;
typedef __attribute__((ext_vector_type(4))) float f32x4;

#define MFMA16(a, b, c) __builtin_amdgcn_mfma_f32_16x16x32_bf16((a), (b), (c), 0, 0, 0)

__device__ __forceinline__ unsigned short f2bf(float f) {
  union { float f; unsigned int u; } v; v.f = f;
  return (unsigned short)((v.u + 0x7fffu + ((v.u >> 16) & 1u)) >> 16);
}

__device__ __forceinline__ void gload_lds16(const void* g, void* l) {
  __builtin_amdgcn_global_load_lds((__attribute__((address_space(1))) void*)g,
                                   (__attribute__((address_space(3))) void*)l,
                                   16, 0, 0);
}

// ---------------- weight fp32 -> bf16 conversion (4 arrays in one launch) ----
struct CvtArgs {
  const float* s0; const float* s1; const float* s2; const float* s3;
  unsigned short* d0; unsigned short* d1; unsigned short* d2; unsigned short* d3;
};

__global__ __launch_bounds__(256) void cvt_weights(CvtArgs a) {
  const long N0 = 1048576, N1 = 1048576, N2 = 4194304;  // wq, wo, w1 (w2 rest)
  long i = ((long)blockIdx.x * 256 + threadIdx.x) * 4;
  const float* s; unsigned short* d; long off;
  if (i < N0)                { s = a.s0; d = a.d0; off = i; }
  else if (i < N0 + N1)      { s = a.s1; d = a.d1; off = i - N0; }
  else if (i < N0 + N1 + N2) { s = a.s2; d = a.d2; off = i - N0 - N1; }
  else                       { s = a.s3; d = a.d3; off = i - N0 - N1 - N2; }
  float4 v = *(const float4*)(s + off);
  ushort4 o;
  o.x = f2bf(v.x); o.y = f2bf(v.y); o.z = f2bf(v.z); o.w = f2bf(v.w);
  *(ushort4*)(d + off) = o;
}

// ---------------- LayerNorm (ddof=1, eps added to std), fp32 in -> bf16 out --
__global__ __launch_bounds__(256) void ln_kernel(
    const float* __restrict__ x,
    const float* __restrict__ alpha, const float* __restrict__ beta,
    unsigned short* __restrict__ out) {
  const int row = blockIdx.x;
  const int tid = threadIdx.x;
  const float4 v = ((const float4*)(x + (size_t)row * 1024))[tid];
  float s  = v.x + v.y + v.z + v.w;
  float sq = v.x * v.x + v.y * v.y + v.z * v.z + v.w * v.w;
  #pragma unroll
  for (int d = 32; d >= 1; d >>= 1) {
    s  += __shfl_xor(s, d, 64);
    sq += __shfl_xor(sq, d, 64);
  }
  __shared__ float red[8];
  const int w = tid >> 6;
  if ((tid & 63) == 0) { red[w] = s; red[4 + w] = sq; }
  __syncthreads();
  s  = red[0] + red[1] + red[2] + red[3];
  sq = red[4] + red[5] + red[6] + red[7];
  const float mean = s * (1.f / 1024.f);
  float var = (sq - s * mean) * (1.f / 1023.f);
  var = fmaxf(var, 0.f);
  const float rs = alpha[0] / (sqrtf(var) + 1e-6f);
  const float bb = beta[0];
  ushort4 o;
  o.x = f2bf((v.x - mean) * rs + bb);
  o.y = f2bf((v.y - mean) * rs + bb);
  o.z = f2bf((v.z - mean) * rs + bb);
  o.w = f2bf((v.w - mean) * rs + bb);
  ((ushort4*)out)[(size_t)row * 256 + tid] = o;
}

// ---------------- GEMM: C[M,N] = A[M,K](bf16) @ B[N,K]^T(bf16) + bias (+res) -
// m97 structure: 128x128 tile, BK=64, 4 waves (2x2), 4x4 16x16x32 frags/wave.
template <int OUT_BF16, int RELU>
__global__ __launch_bounds__(256) void gemm_bt(
    const unsigned short* __restrict__ A, int lda,
    const unsigned short* __restrict__ B, int ldb,
    const float* __restrict__ bias,
    const float* __restrict__ residual,  // may be null; fp32 [M,N]
    void* __restrict__ Cout,
    int M, int N, int K) {
  __shared__ __align__(16) unsigned short As[128 * 64];
  __shared__ __align__(16) unsigned short Bs[128 * 64];
  const int tid = threadIdx.x;
  const int w = tid >> 6, lane = tid & 63;
  const int row0 = blockIdx.y * 128, col0 = blockIdx.x * 128;
  const int wm = (w >> 1) * 64, wn = (w & 1) * 64;
  const int lrow = lane & 15, lk8 = (lane >> 4) * 8;
  const int srow = lane >> 3, scol = (lane & 7) * 8;
  f32x4 acc[4][4] = {};
  for (int k0 = 0; k0 < K; k0 += 64) {
    __syncthreads();
    #pragma unroll
    for (int i = 0; i < 4; ++i) {
      const int chunk = i * 4 + w;       // 16 chunks of 8 rows, 1KB each
      const int r = chunk * 8 + srow;
      gload_lds16(A + (size_t)(row0 + r) * lda + k0 + scol, (char*)As + chunk * 1024);
      gload_lds16(B + (size_t)(col0 + r) * ldb + k0 + scol, (char*)Bs + chunk * 1024);
    }
    asm volatile("s_waitcnt vmcnt(0)" ::: "memory");
    __syncthreads();
    #pragma unroll
    for (int kk = 0; kk < 2; ++kk) {
      short8 a[4], b[4];
      #pragma unroll
      for (int m = 0; m < 4; ++m)
        a[m] = *(const short8*)&As[(wm + m * 16 + lrow) * 64 + kk * 32 + lk8];
      #pragma unroll
      for (int n = 0; n < 4; ++n)
        b[n] = *(const short8*)&Bs[(wn + n * 16 + lrow) * 64 + kk * 32 + lk8];
      #pragma unroll
      for (int m = 0; m < 4; ++m)
        #pragma unroll
        for (int n = 0; n < 4; ++n)
          acc[m][n] = MFMA16(a[m], b[n], acc[m][n]);
    }
  }
  const int g4 = (lane >> 4) << 2;
  #pragma unroll
  for (int n = 0; n < 4; ++n) {
    const int col = col0 + wn + n * 16 + lrow;
    const float bv = bias[col];
    #pragma unroll
    for (int m = 0; m < 4; ++m) {
      const int rbase = row0 + wm + m * 16 + g4;
      #pragma unroll
      for (int r = 0; r < 4; ++r) {
        float v = acc[m][n][r] + bv;
        if (RELU) v = fmaxf(v, 0.f);
        const size_t idx = (size_t)(rbase + r) * N + col;
        if (residual) v += residual[idx];
        if (OUT_BF16) ((unsigned short*)Cout)[idx] = f2bf(v);
        else          ((float*)Cout)[idx] = v;
      }
    }
  }
}

// ---------------- q [B,S,1024] -> qT [B*H, 64, 1024] (per-head d-major) ------
__global__ __launch_bounds__(256) void transpose_q(
    const unsigned short* __restrict__ q, unsigned short* __restrict__ qT) {
  const int st = blockIdx.x, bh = blockIdx.y;
  const int b = bh >> 4, h = bh & 15;
  __shared__ __align__(16) unsigned short tile[64][80];
  const int tid = threadIdx.x;
  const unsigned short* src = q + ((size_t)(b * 1024 + st * 64)) * 1024 + h * 64;
  #pragma unroll
  for (int j = 0; j < 2; ++j) {
    const int u = tid + j * 256;          // 0..511
    const int sl = u >> 3, d8 = (u & 7) * 8;
    *(short8*)&tile[sl][d8] = *(const short8*)&src[(size_t)sl * 1024 + d8];
  }
  __syncthreads();
  unsigned short* dst = qT + ((size_t)(bh * 64)) * 1024 + st * 64;
  #pragma unroll
  for (int j = 0; j < 2; ++j) {
    const int u = tid + j * 256;
    const int dl = u >> 3, s8 = (u & 7) * 8;
    short8 o;
    #pragma unroll
    for (int i = 0; i < 8; ++i) o[i] = (short)tile[s8 + i][dl];
    *(short8*)&dst[(size_t)dl * 1024 + s8] = o;
  }
}

// ---------------- flash attention, K=V=Q (reference bug reproduced) ----------
// Block: (qtile, b*h). 4 waves, each owns 32 q-rows. dk=64, S=1024.
__global__ __launch_bounds__(256) void attn_kernel(
    const unsigned short* __restrict__ q,    // [B,S,1024] bf16
    const unsigned short* __restrict__ qT,   // [B*H,64,1024] bf16
    const int* __restrict__ mask,            // [B,1024]
    unsigned short* __restrict__ ctx) {      // [B,S,1024] bf16
  __shared__ __align__(16) unsigned short Pl[4][32][136];  // per-wave P, padded
  const int qt = blockIdx.x, bh = blockIdx.y;
  const int b = bh >> 4, h = bh & 15;
  const int tid = threadIdx.x, w = tid >> 6, lane = tid & 63;
  const int lrow = lane & 15, lk8 = (lane >> 4) * 8, g4 = (lane >> 4) * 4;
  const int q0 = qt * 128 + w * 32;
  const size_t qbase = (size_t)b * (1024 * 1024) + h * 64;
  short8 qa[2][2];
  #pragma unroll
  for (int mf = 0; mf < 2; ++mf)
    #pragma unroll
    for (int kk = 0; kk < 2; ++kk)
      qa[mf][kk] = *(const short8*)&q[qbase + (size_t)(q0 + mf * 16 + lrow) * 1024 + kk * 32 + lk8];
  float mrun[2][4], lrun[2][4];
  f32x4 Oa[2][4];
  #pragma unroll
  for (int mf = 0; mf < 2; ++mf)
    #pragma unroll
    for (int r = 0; r < 4; ++r) { mrun[mf][r] = -1e30f; lrun[mf][r] = 0.f; }
  #pragma unroll
  for (int mf = 0; mf < 2; ++mf)
    #pragma unroll
    for (int nf = 0; nf < 4; ++nf) Oa[mf][nf] = (f32x4){0.f, 0.f, 0.f, 0.f};

  for (int kt = 0; kt < 8; ++kt) {
    const int k0 = kt * 128;
    // --- S = (Q K^T) for this 128-col tile ---
    f32x4 s[2][8];
    #pragma unroll
    for (int mf = 0; mf < 2; ++mf)
      #pragma unroll
      for (int nf = 0; nf < 8; ++nf) s[mf][nf] = (f32x4){0.f, 0.f, 0.f, 0.f};
    #pragma unroll
    for (int nf = 0; nf < 8; ++nf) {
      #pragma unroll
      for (int kk = 0; kk < 2; ++kk) {
        const short8 kb = *(const short8*)&q[qbase + (size_t)(k0 + nf * 16 + lrow) * 1024 + kk * 32 + lk8];
        s[0][nf] = MFMA16(qa[0][kk], kb, s[0][nf]);
        s[1][nf] = MFMA16(qa[1][kk], kb, s[1][nf]);
      }
    }
    // --- scale + mask ---
    float mb[8];
    #pragma unroll
    for (int nf = 0; nf < 8; ++nf)
      mb[nf] = mask[b * 1024 + k0 + nf * 16 + lrow] ? 0.f : -1e9f;
    float tmax[2][4];
    #pragma unroll
    for (int mf = 0; mf < 2; ++mf)
      #pragma unroll
      for (int r = 0; r < 4; ++r) tmax[mf][r] = -1e30f;
    #pragma unroll
    for (int mf = 0; mf < 2; ++mf)
      #pragma unroll
      for (int nf = 0; nf < 8; ++nf)
        #pragma unroll
        for (int r = 0; r < 4; ++r) {
          const float v = s[mf][nf][r] * 0.125f + mb[nf];
          s[mf][nf][r] = v;
          tmax[mf][r] = fmaxf(tmax[mf][r], v);
        }
    // --- online softmax: row reduce over 16 lanes ---
    #pragma unroll
    for (int mf = 0; mf < 2; ++mf)
      #pragma unroll
      for (int r = 0; r < 4; ++r) {
        #pragma unroll
        for (int d = 1; d < 16; d <<= 1)
          tmax[mf][r] = fmaxf(tmax[mf][r], __shfl_xor(tmax[mf][r], d, 64));
        const float mn = fmaxf(mrun[mf][r], tmax[mf][r]);
        const float corr = __expf(mrun[mf][r] - mn);
        mrun[mf][r] = mn;
        lrun[mf][r] *= corr;
        #pragma unroll
        for (int nf = 0; nf < 4; ++nf) Oa[mf][nf][r] *= corr;
      }
    float tsum[2][4] = {{0, 0, 0, 0}, {0, 0, 0, 0}};
    #pragma unroll
    for (int mf = 0; mf < 2; ++mf)
      #pragma unroll
      for (int nf = 0; nf < 8; ++nf)
        #pragma unroll
        for (int r = 0; r < 4; ++r) {
          const float p = __expf(s[mf][nf][r] - mrun[mf][r]);
          tsum[mf][r] += p;
          Pl[w][mf * 16 + g4 + r][nf * 16 + lrow] = f2bf(p);
        }
    #pragma unroll
    for (int mf = 0; mf < 2; ++mf)
      #pragma unroll
      for (int r = 0; r < 4; ++r) {
        #pragma unroll
        for (int d = 1; d < 16; d <<= 1)
          tsum[mf][r] += __shfl_xor(tsum[mf][r], d, 64);
        lrun[mf][r] += tsum[mf][r];
      }
    // --- O += P @ V  (V = Q, k-contiguous via qT) ---
    #pragma unroll
    for (int ks = 0; ks < 4; ++ks) {
      short8 pa[2];
      pa[0] = *(const short8*)&Pl[w][lrow][ks * 32 + lk8];
      pa[1] = *(const short8*)&Pl[w][16 + lrow][ks * 32 + lk8];
      #pragma unroll
      for (int nf = 0; nf < 4; ++nf) {
        const short8 vb = *(const short8*)&qT[(size_t)(bh * 64 + nf * 16 + lrow) * 1024 + k0 + ks * 32 + lk8];
        Oa[0][nf] = MFMA16(pa[0], vb, Oa[0][nf]);
        Oa[1][nf] = MFMA16(pa[1], vb, Oa[1][nf]);
      }
    }
  }
  #pragma unroll
  for (int mf = 0; mf < 2; ++mf)
    #pragma unroll
    for (int nf = 0; nf < 4; ++nf)
      #pragma unroll
      for (int r = 0; r < 4; ++r) {
        const int row = q0 + mf * 16 + g4 + r;
        const int col = h * 64 + nf * 16 + lrow;
        const float o = Oa[mf][nf][r] / lrun[mf][r];
        ctx[((size_t)b * 1024 + row) * 1024 + col] = f2bf(o);
      }
}

// ---------------- launch ----------------------------------------------------
extern "C" void kernel_launch(void* const* d_in, const int* in_sizes, int n_in,
                              void* d_out, int out_size, void* d_ws, size_t ws_size,
                              hipStream_t stream) {
  const float* x    = (const float*)d_in[0];
  const int*   mask = (const int*)d_in[1];
  const float* wq   = (const float*)d_in[2];
  const float* bq   = (const float*)d_in[3];
  const float* wo   = (const float*)d_in[8];
  const float* bo   = (const float*)d_in[9];
  const float* w1   = (const float*)d_in[10];
  const float* b1   = (const float*)d_in[11];
  const float* w2   = (const float*)d_in[12];
  const float* b2   = (const float*)d_in[13];
  const float* ln1a = (const float*)d_in[14];
  const float* ln1b = (const float*)d_in[15];
  const float* ln2a = (const float*)d_in[16];
  const float* ln2b = (const float*)d_in[17];
  float* out = (float*)d_out;

  char* ws = (char*)d_ws;
  unsigned short* wq_b  = (unsigned short*)(ws);                  //  2 MB
  unsigned short* wo_b  = (unsigned short*)(ws + (2l << 20));     //  2 MB
  unsigned short* w1_b  = (unsigned short*)(ws + (4l << 20));     //  8 MB
  unsigned short* w2_b  = (unsigned short*)(ws + (12l << 20));    //  8 MB
  unsigned short* n_b   = (unsigned short*)(ws + (20l << 20));    // 16 MB (n, then n2)
  unsigned short* q_b   = (unsigned short*)(ws + (36l << 20));    // 16 MB
  unsigned short* qT_b  = (unsigned short*)(ws + (52l << 20));    // 16 MB
  unsigned short* ctx_b = (unsigned short*)(ws + (68l << 20));    // 16 MB
  unsigned short* h_b   = (unsigned short*)(ws + (84l << 20));    // 64 MB

  CvtArgs ca{wq, wo, w1, w2, wq_b, wo_b, w1_b, w2_b};
  cvt_weights<<<10240, 256, 0, stream>>>(ca);
  ln_kernel<<<8192, 256, 0, stream>>>(x, ln1a, ln1b, n_b);
  gemm_bt<1, 0><<<dim3(8, 64), 256, 0, stream>>>(n_b, 1024, wq_b, 1024, bq, nullptr, q_b, 8192, 1024, 1024);
  transpose_q<<<dim3(16, 128), 256, 0, stream>>>(q_b, qT_b);
  attn_kernel<<<dim3(8, 128), 256, 0, stream>>>(q_b, qT_b, mask, ctx_b);
  gemm_bt<0, 0><<<dim3(8, 64), 256, 0, stream>>>(ctx_b, 1024, wo_b, 1024, bo, x, out, 8192, 1024, 1024);
  ln_kernel<<<8192, 256, 0, stream>>>(out, ln2a, ln2b, n_b);
  gemm_bt<1, 1><<<dim3(32, 64), 256, 0, stream>>>(n_b, 1024, w1_b, 1024, b1, nullptr, h_b, 8192, 4096, 1024);
  gemm_bt<0, 0><<<dim3(8, 64), 256, 0, stream>>>(h_b, 4096, w2_b, 4096, b2, out, out, 8192, 1024, 4096);
}

// Round 2
// 461.614 us; speedup vs baseline: 1.1246x; 1.1246x over previous
//
#include <hip/hip_runtime.h>

typedef __attribute__((ext_vector_type(8))) short short8;
typedef __attribute__((ext_vector_type(4))) float f32x4;

#define MFMA16(a, b, c) __builtin_amdgcn_mfma_f32_16x16x32_bf16((a), (b), (c), 0, 0, 0)

__device__ __forceinline__ unsigned short f2bf(float f) {
  union { float f; unsigned int u; } v; v.f = f;
  return (unsigned short)((v.u + 0x7fffu + ((v.u >> 16) & 1u)) >> 16);
}

__device__ __forceinline__ void gload_lds16(const void* g, void* l) {
  __builtin_amdgcn_global_load_lds((__attribute__((address_space(1))) void*)g,
                                   (__attribute__((address_space(3))) void*)l,
                                   16, 0, 0);
}

// ---------------- weight fp32 -> bf16 conversion (4 arrays in one launch) ----
struct CvtArgs {
  const float* s0; const float* s1; const float* s2; const float* s3;
  unsigned short* d0; unsigned short* d1; unsigned short* d2; unsigned short* d3;
};

__global__ __launch_bounds__(256) void cvt_weights(CvtArgs a) {
  const long N0 = 1048576, N1 = 1048576, N2 = 4194304;  // wq, wo, w1 (w2 rest)
  long i = ((long)blockIdx.x * 256 + threadIdx.x) * 4;
  const float* s; unsigned short* d; long off;
  if (i < N0)                { s = a.s0; d = a.d0; off = i; }
  else if (i < N0 + N1)      { s = a.s1; d = a.d1; off = i - N0; }
  else if (i < N0 + N1 + N2) { s = a.s2; d = a.d2; off = i - N0 - N1; }
  else                       { s = a.s3; d = a.d3; off = i - N0 - N1 - N2; }
  float4 v = *(const float4*)(s + off);
  ushort4 o;
  o.x = f2bf(v.x); o.y = f2bf(v.y); o.z = f2bf(v.z); o.w = f2bf(v.w);
  *(ushort4*)(d + off) = o;
}

// ---------------- LayerNorm (ddof=1, eps added to std), fp32 in -> bf16 out --
__global__ __launch_bounds__(256) void ln_kernel(
    const float* __restrict__ x,
    const float* __restrict__ alpha, const float* __restrict__ beta,
    unsigned short* __restrict__ out) {
  const int row = blockIdx.x;
  const int tid = threadIdx.x;
  const float4 v = ((const float4*)(x + (size_t)row * 1024))[tid];
  float s  = v.x + v.y + v.z + v.w;
  float sq = v.x * v.x + v.y * v.y + v.z * v.z + v.w * v.w;
  #pragma unroll
  for (int d = 32; d >= 1; d >>= 1) {
    s  += __shfl_xor(s, d, 64);
    sq += __shfl_xor(sq, d, 64);
  }
  __shared__ float red[8];
  const int w = tid >> 6;
  if ((tid & 63) == 0) { red[w] = s; red[4 + w] = sq; }
  __syncthreads();
  s  = red[0] + red[1] + red[2] + red[3];
  sq = red[4] + red[5] + red[6] + red[7];
  const float mean = s * (1.f / 1024.f);
  float var = (sq - s * mean) * (1.f / 1023.f);
  var = fmaxf(var, 0.f);
  const float rs = alpha[0] / (sqrtf(var) + 1e-6f);
  const float bb = beta[0];
  ushort4 o;
  o.x = f2bf((v.x - mean) * rs + bb);
  o.y = f2bf((v.y - mean) * rs + bb);
  o.z = f2bf((v.z - mean) * rs + bb);
  o.w = f2bf((v.w - mean) * rs + bb);
  ((ushort4*)out)[(size_t)row * 256 + tid] = o;
}

// ---------------- GEMM: C[M,N] = A[M,K](bf16) @ B[N,K]^T(bf16) + bias (+res) -
template <int OUT_BF16, int RELU>
__global__ __launch_bounds__(256) void gemm_bt(
    const unsigned short* __restrict__ A, int lda,
    const unsigned short* __restrict__ B, int ldb,
    const float* __restrict__ bias,
    const float* __restrict__ residual,  // may be null; fp32 [M,N]
    void* __restrict__ Cout,
    int M, int N, int K) {
  __shared__ __align__(16) unsigned short As[128 * 64];
  __shared__ __align__(16) unsigned short Bs[128 * 64];
  const int tid = threadIdx.x;
  const int w = tid >> 6, lane = tid & 63;
  const int row0 = blockIdx.y * 128, col0 = blockIdx.x * 128;
  const int wm = (w >> 1) * 64, wn = (w & 1) * 64;
  const int lrow = lane & 15, lk8 = (lane >> 4) * 8;
  const int srow = lane >> 3, scol = (lane & 7) * 8;
  f32x4 acc[4][4] = {};
  for (int k0 = 0; k0 < K; k0 += 64) {
    __syncthreads();
    #pragma unroll
    for (int i = 0; i < 4; ++i) {
      const int chunk = i * 4 + w;       // 16 chunks of 8 rows, 1KB each
      const int r = chunk * 8 + srow;
      gload_lds16(A + (size_t)(row0 + r) * lda + k0 + scol, (char*)As + chunk * 1024);
      gload_lds16(B + (size_t)(col0 + r) * ldb + k0 + scol, (char*)Bs + chunk * 1024);
    }
    asm volatile("s_waitcnt vmcnt(0)" ::: "memory");
    __syncthreads();
    #pragma unroll
    for (int kk = 0; kk < 2; ++kk) {
      short8 a[4], b[4];
      #pragma unroll
      for (int m = 0; m < 4; ++m)
        a[m] = *(const short8*)&As[(wm + m * 16 + lrow) * 64 + kk * 32 + lk8];
      #pragma unroll
      for (int n = 0; n < 4; ++n)
        b[n] = *(const short8*)&Bs[(wn + n * 16 + lrow) * 64 + kk * 32 + lk8];
      #pragma unroll
      for (int m = 0; m < 4; ++m)
        #pragma unroll
        for (int n = 0; n < 4; ++n)
          acc[m][n] = MFMA16(a[m], b[n], acc[m][n]);
    }
  }
  const int g4 = (lane >> 4) << 2;
  #pragma unroll
  for (int n = 0; n < 4; ++n) {
    const int col = col0 + wn + n * 16 + lrow;
    const float bv = bias[col];
    #pragma unroll
    for (int m = 0; m < 4; ++m) {
      const int rbase = row0 + wm + m * 16 + g4;
      #pragma unroll
      for (int r = 0; r < 4; ++r) {
        float v = acc[m][n][r] + bv;
        if (RELU) v = fmaxf(v, 0.f);
        const size_t idx = (size_t)(rbase + r) * N + col;
        if (residual) v += residual[idx];
        if (OUT_BF16) ((unsigned short*)Cout)[idx] = f2bf(v);
        else          ((float*)Cout)[idx] = v;
      }
    }
  }
}

// ---------------- q [B,S,1024] -> qT [B*H, 64, 1024] (per-head d-major) ------
__global__ __launch_bounds__(256) void transpose_q(
    const unsigned short* __restrict__ q, unsigned short* __restrict__ qT) {
  const int st = blockIdx.x, bh = blockIdx.y;
  const int b = bh >> 4, h = bh & 15;
  __shared__ __align__(16) unsigned short tile[64][80];
  const int tid = threadIdx.x;
  const unsigned short* src = q + ((size_t)(b * 1024 + st * 64)) * 1024 + h * 64;
  #pragma unroll
  for (int j = 0; j < 2; ++j) {
    const int u = tid + j * 256;          // 0..511
    const int sl = u >> 3, d8 = (u & 7) * 8;
    *(short8*)&tile[sl][d8] = *(const short8*)&src[(size_t)sl * 1024 + d8];
  }
  __syncthreads();
  unsigned short* dst = qT + ((size_t)(bh * 64)) * 1024 + st * 64;
  #pragma unroll
  for (int j = 0; j < 2; ++j) {
    const int u = tid + j * 256;
    const int dl = u >> 3, s8 = (u & 7) * 8;
    short8 o;
    #pragma unroll
    for (int i = 0; i < 8; ++i) o[i] = (short)tile[s8 + i][dl];
    *(short8*)&dst[(size_t)dl * 1024 + s8] = o;
  }
}

// ---------------- flash attention v2: swapped QK^T, K=V=Q ------------------
// Block: (qtile, b*h). 4 waves x 32 q-rows. dk=64, S=1024, KVBLK=64.
// St = mfma(K,Q): lane holds P[k][q=lane&15]. Softmax lane-local + 2 shfl.
// P -> LDS [32 q][64 k] bf16, 16B-unit XOR swizzle (unit ^= lane&7):
//   write unit 2kf+(g>>1), 8B sub-slot (g&1);  read unit 4ks+g (b128).
__global__ __launch_bounds__(256) void attn_kernel(
    const unsigned short* __restrict__ q,    // [B,S,1024] bf16
    const unsigned short* __restrict__ qT,   // [B*H,64,1024] bf16
    const int* __restrict__ mask,            // [B,1024]
    unsigned short* __restrict__ ctx) {      // [B,S,1024] bf16
  __shared__ __align__(16) unsigned short Pl[4][32 * 64];
  const int qt = blockIdx.x, bh = blockIdx.y;
  const int b = bh >> 4, h = bh & 15;
  const int tid = threadIdx.x, w = tid >> 6, lane = tid & 63;
  const int lq = lane & 15;        // q-col of St / A-row of PV / d-col of O
  const int g = lane >> 4;         // lane group
  const int lk8 = g * 8;
  const int swz = lane & 7;
  const int q0 = qt * 128 + w * 32;
  const size_t qbase = (size_t)b * (1024 * 1024) + h * 64;
  char* Pw = (char*)Pl[w];

  // Q fragments (B-operand): col=lq -> q-row q0+16qf+lq
  short8 qa[2][2];
  #pragma unroll
  for (int qf = 0; qf < 2; ++qf)
    #pragma unroll
    for (int kk = 0; kk < 2; ++kk)
      qa[qf][kk] = *(const short8*)&q[qbase + (size_t)(q0 + qf * 16 + lq) * 1024 + kk * 32 + lk8];

  float mrun[2] = {-1e30f, -1e30f};
  float lrun[2] = {0.f, 0.f};
  f32x4 Oa[2][4];
  #pragma unroll
  for (int mf = 0; mf < 2; ++mf)
    #pragma unroll
    for (int nf = 0; nf < 4; ++nf) Oa[mf][nf] = (f32x4){0.f, 0.f, 0.f, 0.f};

  const int* mrow = mask + b * 1024;

  for (int kt = 0; kt < 16; ++kt) {
    const int k0 = kt * 64;
    // --- St = K Q^T for 64 k-rows x 32 q-cols ---
    f32x4 s[2][4];
    #pragma unroll
    for (int qf = 0; qf < 2; ++qf)
      #pragma unroll
      for (int kf = 0; kf < 4; ++kf) s[qf][kf] = (f32x4){0.f, 0.f, 0.f, 0.f};
    #pragma unroll
    for (int kf = 0; kf < 4; ++kf) {
      const size_t ko = qbase + (size_t)(k0 + kf * 16 + lq) * 1024 + lk8;
      const short8 ka0 = *(const short8*)&q[ko];
      const short8 ka1 = *(const short8*)&q[ko + 32];
      s[0][kf] = MFMA16(ka0, qa[0][0], s[0][kf]);
      s[0][kf] = MFMA16(ka1, qa[0][1], s[0][kf]);
      s[1][kf] = MFMA16(ka0, qa[1][0], s[1][kf]);
      s[1][kf] = MFMA16(ka1, qa[1][1], s[1][kf]);
    }
    // --- scale + mask + lane-local max (k = k0 + 16kf + 4g + r) ---
    float pmax[2] = {-1e30f, -1e30f};
    #pragma unroll
    for (int kf = 0; kf < 4; ++kf) {
      const int4 mv = *(const int4*)&mrow[k0 + kf * 16 + g * 4];
      float madd[4];
      madd[0] = mv.x ? 0.f : -1e9f; madd[1] = mv.y ? 0.f : -1e9f;
      madd[2] = mv.z ? 0.f : -1e9f; madd[3] = mv.w ? 0.f : -1e9f;
      #pragma unroll
      for (int qf = 0; qf < 2; ++qf)
        #pragma unroll
        for (int r = 0; r < 4; ++r) {
          const float v = s[qf][kf][r] * 0.125f + madd[r];
          s[qf][kf][r] = v;
          pmax[qf] = fmaxf(pmax[qf], v);
        }
    }
    #pragma unroll
    for (int qf = 0; qf < 2; ++qf) {
      pmax[qf] = fmaxf(pmax[qf], __shfl_xor(pmax[qf], 16, 64));
      pmax[qf] = fmaxf(pmax[qf], __shfl_xor(pmax[qf], 32, 64));
    }
    // --- defer-max (T13): rescale O only when max grew past THR=8 ---
    const int ok = (pmax[0] <= mrun[0] + 8.f) && (pmax[1] <= mrun[1] + 8.f);
    if (!__all(ok)) {
      float corr[2];
      #pragma unroll
      for (int qf = 0; qf < 2; ++qf) {
        const float mn = fmaxf(mrun[qf], pmax[qf]);
        corr[qf] = __expf(mrun[qf] - mn);
        mrun[qf] = mn;
        lrun[qf] *= corr[qf];
      }
      #pragma unroll
      for (int mf = 0; mf < 2; ++mf)
        #pragma unroll
        for (int r = 0; r < 4; ++r) {
          const float c = __shfl(corr[mf], g * 4 + r, 64);
          #pragma unroll
          for (int nf = 0; nf < 4; ++nf) Oa[mf][nf][r] *= c;
        }
    }
    // --- P = exp(s - m), sum, pack -> LDS (swizzled b64 writes) ---
    float tsum[2] = {0.f, 0.f};
    #pragma unroll
    for (int qf = 0; qf < 2; ++qf) {
      const int rowoff = (qf * 16 + lq) * 128;
      #pragma unroll
      for (int kf = 0; kf < 4; ++kf) {
        float p[4];
        #pragma unroll
        for (int r = 0; r < 4; ++r) {
          p[r] = __expf(s[qf][kf][r] - mrun[qf]);
          tsum[qf] += p[r];
        }
        ushort4 pk;
        pk.x = f2bf(p[0]); pk.y = f2bf(p[1]); pk.z = f2bf(p[2]); pk.w = f2bf(p[3]);
        *(ushort4*)(Pw + rowoff + (((2 * kf + (g >> 1)) ^ swz) << 4) + ((g & 1) << 3)) = pk;
      }
    }
    #pragma unroll
    for (int qf = 0; qf < 2; ++qf) {
      tsum[qf] += __shfl_xor(tsum[qf], 16, 64);
      tsum[qf] += __shfl_xor(tsum[qf], 32, 64);
      lrun[qf] += tsum[qf];
    }
    // --- O += P @ V (A = P from LDS b128, B = V from qT) ---
    #pragma unroll
    for (int ks = 0; ks < 2; ++ks) {
      short8 pa[2];
      #pragma unroll
      for (int mf = 0; mf < 2; ++mf)
        pa[mf] = *(const short8*)(Pw + (mf * 16 + lq) * 128 + (((4 * ks + g) ^ swz) << 4));
      #pragma unroll
      for (int nf = 0; nf < 4; ++nf) {
        const short8 vb = *(const short8*)&qT[(size_t)(bh * 64 + nf * 16 + lq) * 1024 + k0 + ks * 32 + lk8];
        Oa[0][nf] = MFMA16(pa[0], vb, Oa[0][nf]);
        Oa[1][nf] = MFMA16(pa[1], vb, Oa[1][nf]);
      }
    }
  }
  // --- epilogue: divide by l (broadcast per O-row) and store ---
  #pragma unroll
  for (int mf = 0; mf < 2; ++mf) {
    #pragma unroll
    for (int r = 0; r < 4; ++r) {
      const float linv = 1.f / __shfl(lrun[mf], g * 4 + r, 64);
      const int row = q0 + mf * 16 + g * 4 + r;
      #pragma unroll
      for (int nf = 0; nf < 4; ++nf) {
        const int col = h * 64 + nf * 16 + lq;
        ctx[((size_t)b * 1024 + row) * 1024 + col] = f2bf(Oa[mf][nf][r] * linv);
      }
    }
  }
}

// ---------------- launch ----------------------------------------------------
extern "C" void kernel_launch(void* const* d_in, const int* in_sizes, int n_in,
                              void* d_out, int out_size, void* d_ws, size_t ws_size,
                              hipStream_t stream) {
  const float* x    = (const float*)d_in[0];
  const int*   mask = (const int*)d_in[1];
  const float* wq   = (const float*)d_in[2];
  const float* bq   = (const float*)d_in[3];
  const float* wo   = (const float*)d_in[8];
  const float* bo   = (const float*)d_in[9];
  const float* w1   = (const float*)d_in[10];
  const float* b1   = (const float*)d_in[11];
  const float* w2   = (const float*)d_in[12];
  const float* b2   = (const float*)d_in[13];
  const float* ln1a = (const float*)d_in[14];
  const float* ln1b = (const float*)d_in[15];
  const float* ln2a = (const float*)d_in[16];
  const float* ln2b = (const float*)d_in[17];
  float* out = (float*)d_out;

  char* ws = (char*)d_ws;
  unsigned short* wq_b  = (unsigned short*)(ws);                  //  2 MB
  unsigned short* wo_b  = (unsigned short*)(ws + (2l << 20));     //  2 MB
  unsigned short* w1_b  = (unsigned short*)(ws + (4l << 20));     //  8 MB
  unsigned short* w2_b  = (unsigned short*)(ws + (12l << 20));    //  8 MB
  unsigned short* n_b   = (unsigned short*)(ws + (20l << 20));    // 16 MB (n, then n2)
  unsigned short* q_b   = (unsigned short*)(ws + (36l << 20));    // 16 MB
  unsigned short* qT_b  = (unsigned short*)(ws + (52l << 20));    // 16 MB
  unsigned short* ctx_b = (unsigned short*)(ws + (68l << 20));    // 16 MB
  unsigned short* h_b   = (unsigned short*)(ws + (84l << 20));    // 64 MB

  CvtArgs ca{wq, wo, w1, w2, wq_b, wo_b, w1_b, w2_b};
  cvt_weights<<<10240, 256, 0, stream>>>(ca);
  ln_kernel<<<8192, 256, 0, stream>>>(x, ln1a, ln1b, n_b);
  gemm_bt<1, 0><<<dim3(8, 64), 256, 0, stream>>>(n_b, 1024, wq_b, 1024, bq, nullptr, q_b, 8192, 1024, 1024);
  transpose_q<<<dim3(16, 128), 256, 0, stream>>>(q_b, qT_b);
  attn_kernel<<<dim3(8, 128), 256, 0, stream>>>(q_b, qT_b, mask, ctx_b);
  gemm_bt<0, 0><<<dim3(8, 64), 256, 0, stream>>>(ctx_b, 1024, wo_b, 1024, bo, x, out, 8192, 1024, 1024);
  ln_kernel<<<8192, 256, 0, stream>>>(out, ln2a, ln2b, n_b);
  gemm_bt<1, 1><<<dim3(32, 64), 256, 0, stream>>>(n_b, 1024, w1_b, 1024, b1, nullptr, h_b, 8192, 4096, 1024);
  gemm_bt<0, 0><<<dim3(8, 64), 256, 0, stream>>>(h_b, 4096, w2_b, 4096, b2, out, out, 8192, 1024, 4096);
}

// Round 3
// 410.826 us; speedup vs baseline: 1.2636x; 1.1236x over previous
//
#include <hip/hip_runtime.h>

typedef __attribute__((ext_vector_type(8))) short short8;
typedef __attribute__((ext_vector_type(4))) float f32x4;

#define MFMA16(a, b, c) __builtin_amdgcn_mfma_f32_16x16x32_bf16((a), (b), (c), 0, 0, 0)

__device__ __forceinline__ unsigned short f2bf(float f) {
  union { float f; unsigned int u; } v; v.f = f;
  return (unsigned short)((v.u + 0x7fffu + ((v.u >> 16) & 1u)) >> 16);
}

__device__ __forceinline__ void gload_lds16(const void* g, void* l) {
  __builtin_amdgcn_global_load_lds((__attribute__((address_space(1))) void*)g,
                                   (__attribute__((address_space(3))) void*)l,
                                   16, 0, 0);
}

// ---------------- weight fp32 -> bf16 conversion (4 arrays in one launch) ----
struct CvtArgs {
  const float* s0; const float* s1; const float* s2; const float* s3;
  unsigned short* d0; unsigned short* d1; unsigned short* d2; unsigned short* d3;
};

__global__ __launch_bounds__(256) void cvt_weights(CvtArgs a) {
  const long N0 = 1048576, N1 = 1048576, N2 = 4194304;  // wq, wo, w1 (w2 rest)
  long i = ((long)blockIdx.x * 256 + threadIdx.x) * 4;
  const float* s; unsigned short* d; long off;
  if (i < N0)                { s = a.s0; d = a.d0; off = i; }
  else if (i < N0 + N1)      { s = a.s1; d = a.d1; off = i - N0; }
  else if (i < N0 + N1 + N2) { s = a.s2; d = a.d2; off = i - N0 - N1; }
  else                       { s = a.s3; d = a.d3; off = i - N0 - N1 - N2; }
  float4 v = *(const float4*)(s + off);
  ushort4 o;
  o.x = f2bf(v.x); o.y = f2bf(v.y); o.z = f2bf(v.z); o.w = f2bf(v.w);
  *(ushort4*)(d + off) = o;
}

// ---------------- LayerNorm (ddof=1, eps added to std), fp32 in -> bf16 out --
__global__ __launch_bounds__(256) void ln_kernel(
    const float* __restrict__ x,
    const float* __restrict__ alpha, const float* __restrict__ beta,
    unsigned short* __restrict__ out) {
  const int row = blockIdx.x;
  const int tid = threadIdx.x;
  const float4 v = ((const float4*)(x + (size_t)row * 1024))[tid];
  float s  = v.x + v.y + v.z + v.w;
  float sq = v.x * v.x + v.y * v.y + v.z * v.z + v.w * v.w;
  #pragma unroll
  for (int d = 32; d >= 1; d >>= 1) {
    s  += __shfl_xor(s, d, 64);
    sq += __shfl_xor(sq, d, 64);
  }
  __shared__ float red[8];
  const int w = tid >> 6;
  if ((tid & 63) == 0) { red[w] = s; red[4 + w] = sq; }
  __syncthreads();
  s  = red[0] + red[1] + red[2] + red[3];
  sq = red[4] + red[5] + red[6] + red[7];
  const float mean = s * (1.f / 1024.f);
  float var = (sq - s * mean) * (1.f / 1023.f);
  var = fmaxf(var, 0.f);
  const float rs = alpha[0] / (sqrtf(var) + 1e-6f);
  const float bb = beta[0];
  ushort4 o;
  o.x = f2bf((v.x - mean) * rs + bb);
  o.y = f2bf((v.y - mean) * rs + bb);
  o.z = f2bf((v.z - mean) * rs + bb);
  o.w = f2bf((v.w - mean) * rs + bb);
  ((ushort4*)out)[(size_t)row * 256 + tid] = o;
}

// ---------------- GEMM: C[M,N] = A[M,K](bf16) @ B[N,K]^T(bf16) + bias (+res) -
template <int OUT_BF16, int RELU>
__global__ __launch_bounds__(256) void gemm_bt(
    const unsigned short* __restrict__ A, int lda,
    const unsigned short* __restrict__ B, int ldb,
    const float* __restrict__ bias,
    const float* __restrict__ residual,  // may be null; fp32 [M,N]
    void* __restrict__ Cout,
    int M, int N, int K) {
  __shared__ __align__(16) unsigned short As[128 * 64];
  __shared__ __align__(16) unsigned short Bs[128 * 64];
  const int tid = threadIdx.x;
  const int w = tid >> 6, lane = tid & 63;
  const int row0 = blockIdx.y * 128, col0 = blockIdx.x * 128;
  const int wm = (w >> 1) * 64, wn = (w & 1) * 64;
  const int lrow = lane & 15, lk8 = (lane >> 4) * 8;
  const int srow = lane >> 3, scol = (lane & 7) * 8;
  f32x4 acc[4][4] = {};
  for (int k0 = 0; k0 < K; k0 += 64) {
    __syncthreads();
    #pragma unroll
    for (int i = 0; i < 4; ++i) {
      const int chunk = i * 4 + w;       // 16 chunks of 8 rows, 1KB each
      const int r = chunk * 8 + srow;
      gload_lds16(A + (size_t)(row0 + r) * lda + k0 + scol, (char*)As + chunk * 1024);
      gload_lds16(B + (size_t)(col0 + r) * ldb + k0 + scol, (char*)Bs + chunk * 1024);
    }
    asm volatile("s_waitcnt vmcnt(0)" ::: "memory");
    __syncthreads();
    #pragma unroll
    for (int kk = 0; kk < 2; ++kk) {
      short8 a[4], b[4];
      #pragma unroll
      for (int m = 0; m < 4; ++m)
        a[m] = *(const short8*)&As[(wm + m * 16 + lrow) * 64 + kk * 32 + lk8];
      #pragma unroll
      for (int n = 0; n < 4; ++n)
        b[n] = *(const short8*)&Bs[(wn + n * 16 + lrow) * 64 + kk * 32 + lk8];
      #pragma unroll
      for (int m = 0; m < 4; ++m)
        #pragma unroll
        for (int n = 0; n < 4; ++n)
          acc[m][n] = MFMA16(a[m], b[n], acc[m][n]);
    }
  }
  const int g4 = (lane >> 4) << 2;
  #pragma unroll
  for (int n = 0; n < 4; ++n) {
    const int col = col0 + wn + n * 16 + lrow;
    const float bv = bias[col];
    #pragma unroll
    for (int m = 0; m < 4; ++m) {
      const int rbase = row0 + wm + m * 16 + g4;
      #pragma unroll
      for (int r = 0; r < 4; ++r) {
        float v = acc[m][n][r] + bv;
        if (RELU) v = fmaxf(v, 0.f);
        const size_t idx = (size_t)(rbase + r) * N + col;
        if (residual) v += residual[idx];
        if (OUT_BF16) ((unsigned short*)Cout)[idx] = f2bf(v);
        else          ((float*)Cout)[idx] = v;
      }
    }
  }
}

// ---------------- q [B,S,1024] -> qT [B*H, 64, 1024] (per-head d-major) ------
__global__ __launch_bounds__(256) void transpose_q(
    const unsigned short* __restrict__ q, unsigned short* __restrict__ qT) {
  const int st = blockIdx.x, bh = blockIdx.y;
  const int b = bh >> 4, h = bh & 15;
  __shared__ __align__(16) unsigned short tile[64][80];
  const int tid = threadIdx.x;
  const unsigned short* src = q + ((size_t)(b * 1024 + st * 64)) * 1024 + h * 64;
  #pragma unroll
  for (int j = 0; j < 2; ++j) {
    const int u = tid + j * 256;          // 0..511
    const int sl = u >> 3, d8 = (u & 7) * 8;
    *(short8*)&tile[sl][d8] = *(const short8*)&src[(size_t)sl * 1024 + d8];
  }
  __syncthreads();
  unsigned short* dst = qT + ((size_t)(bh * 64)) * 1024 + st * 64;
  #pragma unroll
  for (int j = 0; j < 2; ++j) {
    const int u = tid + j * 256;
    const int dl = u >> 3, s8 = (u & 7) * 8;
    short8 o;
    #pragma unroll
    for (int i = 0; i < 8; ++i) o[i] = (short)tile[s8 + i][dl];
    *(short8*)&dst[(size_t)dl * 1024 + s8] = o;
  }
}

// ---------------- flash attention v3: LDS-staged K/V, dbuf, 8 waves ----------
// Grid: 512 blocks (XCD-swizzled), 512 threads = 8 waves x 32 q-rows (256/blk).
// K,V tiles [64 rows][64 el] staged via global_load_lds w/ pre-swizzled source:
// physical unit slot s at row r holds logical 16B-unit u = s ^ (r&7).
__global__ __launch_bounds__(512) void attn_kernel(
    const unsigned short* __restrict__ q,    // [B,S,1024] bf16
    const unsigned short* __restrict__ qT,   // [B*H,64,1024] bf16
    const int* __restrict__ mask,            // [B,1024]
    unsigned short* __restrict__ ctx) {      // [B,S,1024] bf16
  __shared__ __align__(16) unsigned short Ks[2][64 * 64];
  __shared__ __align__(16) unsigned short Vs[2][64 * 64];
  __shared__ __align__(16) unsigned short Pl[8][32 * 64];
  const int id = blockIdx.x;
  const int qt = (id >> 3) & 3;                    // same-bh blocks -> same XCD
  const int bh = (id & 7) * 16 + (id >> 5);
  const int b = bh >> 4, h = bh & 15;
  const int tid = threadIdx.x, w = tid >> 6, lane = tid & 63;
  const int lq = lane & 15;        // q-col of St / P-row / d-col of O
  const int g = lane >> 4;
  const int lk8 = g * 8;
  const int swz = lane & 7;        // = lq & 7
  const int q0 = qt * 256 + w * 32;
  const size_t qbase = (size_t)b * (1024 * 1024) + h * 64;
  const size_t qTb = (size_t)bh * 64 * 1024;
  char* Pw = (char*)Pl[w];
  // staging source: each wave stages one 1KB chunk (8 rows) of K and of V
  const int srow = lane >> 3;                      // 0..7 within chunk
  const int su = (lane & 7) ^ (srow & 7);          // inverse-swizzled unit
  const size_t ksrc = qbase + (size_t)(w * 8 + srow) * 1024 + su * 8;
  const size_t vsrc = qTb + (size_t)(w * 8 + srow) * 1024 + su * 8;

  // Q fragments (B-operand): col=lq -> q-row q0+16qf+lq
  short8 qa[2][2];
  #pragma unroll
  for (int qf = 0; qf < 2; ++qf)
    #pragma unroll
    for (int kk = 0; kk < 2; ++kk)
      qa[qf][kk] = *(const short8*)&q[qbase + (size_t)(q0 + qf * 16 + lq) * 1024 + kk * 32 + lk8];

  float mrun[2] = {-1e30f, -1e30f};
  float lrun[2] = {0.f, 0.f};
  f32x4 Oa[2][4];
  #pragma unroll
  for (int mf = 0; mf < 2; ++mf)
    #pragma unroll
    for (int nf = 0; nf < 4; ++nf) Oa[mf][nf] = (f32x4){0.f, 0.f, 0.f, 0.f};

  const int* mrow = mask + b * 1024;

  // prologue: stage tile 0
  gload_lds16(q + ksrc, (char*)Ks[0] + w * 1024);
  gload_lds16(qT + vsrc, (char*)Vs[0] + w * 1024);
  asm volatile("s_waitcnt vmcnt(0)" ::: "memory");
  __syncthreads();
  int cur = 0;

  for (int kt = 0; kt < 16; ++kt) {
    const int k0 = kt * 64;
    if (kt < 15) {  // prefetch next tile into the other buffer
      gload_lds16(q + ksrc + (size_t)(k0 + 64) * 1024, (char*)Ks[cur ^ 1] + w * 1024);
      gload_lds16(qT + vsrc + (k0 + 64), (char*)Vs[cur ^ 1] + w * 1024);
    }
    const char* Kb = (const char*)Ks[cur];
    const char* Vb = (const char*)Vs[cur];
    // --- St = K Q^T for 64 k-rows x 32 q-cols ---
    f32x4 s[2][4];
    #pragma unroll
    for (int qf = 0; qf < 2; ++qf)
      #pragma unroll
      for (int kf = 0; kf < 4; ++kf) s[qf][kf] = (f32x4){0.f, 0.f, 0.f, 0.f};
    #pragma unroll
    for (int kf = 0; kf < 4; ++kf) {
      const char* kr = Kb + (kf * 16 + lq) * 128;
      const short8 ka0 = *(const short8*)(kr + (((g) ^ swz) << 4));
      const short8 ka1 = *(const short8*)(kr + (((4 + g) ^ swz) << 4));
      s[0][kf] = MFMA16(ka0, qa[0][0], s[0][kf]);
      s[0][kf] = MFMA16(ka1, qa[0][1], s[0][kf]);
      s[1][kf] = MFMA16(ka0, qa[1][0], s[1][kf]);
      s[1][kf] = MFMA16(ka1, qa[1][1], s[1][kf]);
    }
    // --- scale + mask + lane-local max (k = k0 + 16kf + 4g + r) ---
    float pmax[2] = {-1e30f, -1e30f};
    #pragma unroll
    for (int kf = 0; kf < 4; ++kf) {
      const int4 mv = *(const int4*)&mrow[k0 + kf * 16 + g * 4];
      float madd[4];
      madd[0] = mv.x ? 0.f : -1e9f; madd[1] = mv.y ? 0.f : -1e9f;
      madd[2] = mv.z ? 0.f : -1e9f; madd[3] = mv.w ? 0.f : -1e9f;
      #pragma unroll
      for (int qf = 0; qf < 2; ++qf)
        #pragma unroll
        for (int r = 0; r < 4; ++r) {
          const float v = s[qf][kf][r] * 0.125f + madd[r];
          s[qf][kf][r] = v;
          pmax[qf] = fmaxf(pmax[qf], v);
        }
    }
    #pragma unroll
    for (int qf = 0; qf < 2; ++qf) {
      pmax[qf] = fmaxf(pmax[qf], __shfl_xor(pmax[qf], 16, 64));
      pmax[qf] = fmaxf(pmax[qf], __shfl_xor(pmax[qf], 32, 64));
    }
    // --- defer-max (T13): rescale O only when max grew past THR=8 ---
    const int ok = (pmax[0] <= mrun[0] + 8.f) && (pmax[1] <= mrun[1] + 8.f);
    if (!__all(ok)) {
      float corr[2];
      #pragma unroll
      for (int qf = 0; qf < 2; ++qf) {
        const float mn = fmaxf(mrun[qf], pmax[qf]);
        corr[qf] = __expf(mrun[qf] - mn);
        mrun[qf] = mn;
        lrun[qf] *= corr[qf];
      }
      #pragma unroll
      for (int mf = 0; mf < 2; ++mf)
        #pragma unroll
        for (int r = 0; r < 4; ++r) {
          const float c = __shfl(corr[mf], g * 4 + r, 64);
          #pragma unroll
          for (int nf = 0; nf < 4; ++nf) Oa[mf][nf][r] *= c;
        }
    }
    // --- P = exp(s - m), sum, pack -> LDS (swizzled b64 writes) ---
    float tsum[2] = {0.f, 0.f};
    #pragma unroll
    for (int qf = 0; qf < 2; ++qf) {
      const int rowoff = (qf * 16 + lq) * 128;
      #pragma unroll
      for (int kf = 0; kf < 4; ++kf) {
        float p[4];
        #pragma unroll
        for (int r = 0; r < 4; ++r) {
          p[r] = __expf(s[qf][kf][r] - mrun[qf]);
          tsum[qf] += p[r];
        }
        ushort4 pk;
        pk.x = f2bf(p[0]); pk.y = f2bf(p[1]); pk.z = f2bf(p[2]); pk.w = f2bf(p[3]);
        *(ushort4*)(Pw + rowoff + (((2 * kf + (g >> 1)) ^ swz) << 4) + ((g & 1) << 3)) = pk;
      }
    }
    #pragma unroll
    for (int qf = 0; qf < 2; ++qf) {
      tsum[qf] += __shfl_xor(tsum[qf], 16, 64);
      tsum[qf] += __shfl_xor(tsum[qf], 32, 64);
      lrun[qf] += tsum[qf];
    }
    // --- O += P @ V (A = P from LDS b128, B = V from LDS b128) ---
    #pragma unroll
    for (int ks = 0; ks < 2; ++ks) {
      short8 pa[2];
      #pragma unroll
      for (int mf = 0; mf < 2; ++mf)
        pa[mf] = *(const short8*)(Pw + (mf * 16 + lq) * 128 + (((4 * ks + g) ^ swz) << 4));
      #pragma unroll
      for (int nf = 0; nf < 4; ++nf) {
        const short8 vb = *(const short8*)(Vb + (nf * 16 + lq) * 128 + (((4 * ks + g) ^ swz) << 4));
        Oa[0][nf] = MFMA16(pa[0], vb, Oa[0][nf]);
        Oa[1][nf] = MFMA16(pa[1], vb, Oa[1][nf]);
      }
    }
    __syncthreads();  // drains vmcnt+lgkmcnt: next buffer staged, cur free
    cur ^= 1;
  }
  // --- epilogue: divide by l (broadcast per O-row) and store ---
  #pragma unroll
  for (int mf = 0; mf < 2; ++mf) {
    #pragma unroll
    for (int r = 0; r < 4; ++r) {
      const float linv = 1.f / __shfl(lrun[mf], g * 4 + r, 64);
      const int row = q0 + mf * 16 + g * 4 + r;
      #pragma unroll
      for (int nf = 0; nf < 4; ++nf) {
        const int col = h * 64 + nf * 16 + lq;
        ctx[((size_t)b * 1024 + row) * 1024 + col] = f2bf(Oa[mf][nf][r] * linv);
      }
    }
  }
}

// ---------------- launch ----------------------------------------------------
extern "C" void kernel_launch(void* const* d_in, const int* in_sizes, int n_in,
                              void* d_out, int out_size, void* d_ws, size_t ws_size,
                              hipStream_t stream) {
  const float* x    = (const float*)d_in[0];
  const int*   mask = (const int*)d_in[1];
  const float* wq   = (const float*)d_in[2];
  const float* bq   = (const float*)d_in[3];
  const float* wo   = (const float*)d_in[8];
  const float* bo   = (const float*)d_in[9];
  const float* w1   = (const float*)d_in[10];
  const float* b1   = (const float*)d_in[11];
  const float* w2   = (const float*)d_in[12];
  const float* b2   = (const float*)d_in[13];
  const float* ln1a = (const float*)d_in[14];
  const float* ln1b = (const float*)d_in[15];
  const float* ln2a = (const float*)d_in[16];
  const float* ln2b = (const float*)d_in[17];
  float* out = (float*)d_out;

  char* ws = (char*)d_ws;
  unsigned short* wq_b  = (unsigned short*)(ws);                  //  2 MB
  unsigned short* wo_b  = (unsigned short*)(ws + (2l << 20));     //  2 MB
  unsigned short* w1_b  = (unsigned short*)(ws + (4l << 20));     //  8 MB
  unsigned short* w2_b  = (unsigned short*)(ws + (12l << 20));    //  8 MB
  unsigned short* n_b   = (unsigned short*)(ws + (20l << 20));    // 16 MB (n, then n2)
  unsigned short* q_b   = (unsigned short*)(ws + (36l << 20));    // 16 MB
  unsigned short* qT_b  = (unsigned short*)(ws + (52l << 20));    // 16 MB
  unsigned short* ctx_b = (unsigned short*)(ws + (68l << 20));    // 16 MB
  unsigned short* h_b   = (unsigned short*)(ws + (84l << 20));    // 64 MB

  CvtArgs ca{wq, wo, w1, w2, wq_b, wo_b, w1_b, w2_b};
  cvt_weights<<<10240, 256, 0, stream>>>(ca);
  ln_kernel<<<8192, 256, 0, stream>>>(x, ln1a, ln1b, n_b);
  gemm_bt<1, 0><<<dim3(8, 64), 256, 0, stream>>>(n_b, 1024, wq_b, 1024, bq, nullptr, q_b, 8192, 1024, 1024);
  transpose_q<<<dim3(16, 128), 256, 0, stream>>>(q_b, qT_b);
  attn_kernel<<<512, 512, 0, stream>>>(q_b, qT_b, mask, ctx_b);
  gemm_bt<0, 0><<<dim3(8, 64), 256, 0, stream>>>(ctx_b, 1024, wo_b, 1024, bo, x, out, 8192, 1024, 1024);
  ln_kernel<<<8192, 256, 0, stream>>>(out, ln2a, ln2b, n_b);
  gemm_bt<1, 1><<<dim3(32, 64), 256, 0, stream>>>(n_b, 1024, w1_b, 1024, b1, nullptr, h_b, 8192, 4096, 1024);
  gemm_bt<0, 0><<<dim3(8, 64), 256, 0, stream>>>(h_b, 4096, w2_b, 4096, b2, out, out, 8192, 1024, 4096);
}

// Round 4
// 407.159 us; speedup vs baseline: 1.2750x; 1.0090x over previous
//
#include <hip/hip_runtime.h>

typedef __attribute__((ext_vector_type(8))) short short8;
typedef __attribute__((ext_vector_type(4))) float f32x4;

#define MFMA16(a, b, c) __builtin_amdgcn_mfma_f32_16x16x32_bf16((a), (b), (c), 0, 0, 0)

__device__ __forceinline__ unsigned short f2bf(float f) {
  union { float f; unsigned int u; } v; v.f = f;
  return (unsigned short)((v.u + 0x7fffu + ((v.u >> 16) & 1u)) >> 16);
}

__device__ __forceinline__ void gload_lds16(const void* g, void* l) {
  __builtin_amdgcn_global_load_lds((__attribute__((address_space(1))) void*)g,
                                   (__attribute__((address_space(3))) void*)l,
                                   16, 0, 0);
}

// ---------------- weight fp32 -> bf16 conversion (4 arrays in one launch) ----
struct CvtArgs {
  const float* s0; const float* s1; const float* s2; const float* s3;
  unsigned short* d0; unsigned short* d1; unsigned short* d2; unsigned short* d3;
};

__global__ __launch_bounds__(256) void cvt_weights(CvtArgs a) {
  const long N0 = 1048576, N1 = 1048576, N2 = 4194304;  // wq, wo, w1 (w2 rest)
  long i = ((long)blockIdx.x * 256 + threadIdx.x) * 4;
  const float* s; unsigned short* d; long off;
  if (i < N0)                { s = a.s0; d = a.d0; off = i; }
  else if (i < N0 + N1)      { s = a.s1; d = a.d1; off = i - N0; }
  else if (i < N0 + N1 + N2) { s = a.s2; d = a.d2; off = i - N0 - N1; }
  else                       { s = a.s3; d = a.d3; off = i - N0 - N1 - N2; }
  float4 v = *(const float4*)(s + off);
  ushort4 o;
  o.x = f2bf(v.x); o.y = f2bf(v.y); o.z = f2bf(v.z); o.w = f2bf(v.w);
  *(ushort4*)(d + off) = o;
}

// ---------------- LayerNorm (ddof=1, eps added to std), fp32 in -> bf16 out --
__global__ __launch_bounds__(256) void ln_kernel(
    const float* __restrict__ x,
    const float* __restrict__ alpha, const float* __restrict__ beta,
    unsigned short* __restrict__ out) {
  const int row = blockIdx.x;
  const int tid = threadIdx.x;
  const float4 v = ((const float4*)(x + (size_t)row * 1024))[tid];
  float s  = v.x + v.y + v.z + v.w;
  float sq = v.x * v.x + v.y * v.y + v.z * v.z + v.w * v.w;
  #pragma unroll
  for (int d = 32; d >= 1; d >>= 1) {
    s  += __shfl_xor(s, d, 64);
    sq += __shfl_xor(sq, d, 64);
  }
  __shared__ float red[8];
  const int w = tid >> 6;
  if ((tid & 63) == 0) { red[w] = s; red[4 + w] = sq; }
  __syncthreads();
  s  = red[0] + red[1] + red[2] + red[3];
  sq = red[4] + red[5] + red[6] + red[7];
  const float mean = s * (1.f / 1024.f);
  float var = (sq - s * mean) * (1.f / 1023.f);
  var = fmaxf(var, 0.f);
  const float rs = alpha[0] / (sqrtf(var) + 1e-6f);
  const float bb = beta[0];
  ushort4 o;
  o.x = f2bf((v.x - mean) * rs + bb);
  o.y = f2bf((v.y - mean) * rs + bb);
  o.z = f2bf((v.z - mean) * rs + bb);
  o.w = f2bf((v.w - mean) * rs + bb);
  ((ushort4*)out)[(size_t)row * 256 + tid] = o;
}

// ---------------- m97 GEMM (kept for the 1024-col projections) --------------
template <int OUT_BF16, int RELU>
__global__ __launch_bounds__(256) void gemm_bt(
    const unsigned short* __restrict__ A, int lda,
    const unsigned short* __restrict__ B, int ldb,
    const float* __restrict__ bias,
    const float* __restrict__ residual,  // may be null; fp32 [M,N]
    void* __restrict__ Cout,
    int M, int N, int K) {
  __shared__ __align__(16) unsigned short As[128 * 64];
  __shared__ __align__(16) unsigned short Bs[128 * 64];
  const int tid = threadIdx.x;
  const int w = tid >> 6, lane = tid & 63;
  const int row0 = blockIdx.y * 128, col0 = blockIdx.x * 128;
  const int wm = (w >> 1) * 64, wn = (w & 1) * 64;
  const int lrow = lane & 15, lk8 = (lane >> 4) * 8;
  const int srow = lane >> 3, scol = (lane & 7) * 8;
  f32x4 acc[4][4] = {};
  for (int k0 = 0; k0 < K; k0 += 64) {
    __syncthreads();
    #pragma unroll
    for (int i = 0; i < 4; ++i) {
      const int chunk = i * 4 + w;
      const int r = chunk * 8 + srow;
      gload_lds16(A + (size_t)(row0 + r) * lda + k0 + scol, (char*)As + chunk * 1024);
      gload_lds16(B + (size_t)(col0 + r) * ldb + k0 + scol, (char*)Bs + chunk * 1024);
    }
    asm volatile("s_waitcnt vmcnt(0)" ::: "memory");
    __syncthreads();
    #pragma unroll
    for (int kk = 0; kk < 2; ++kk) {
      short8 a[4], b[4];
      #pragma unroll
      for (int m = 0; m < 4; ++m)
        a[m] = *(const short8*)&As[(wm + m * 16 + lrow) * 64 + kk * 32 + lk8];
      #pragma unroll
      for (int n = 0; n < 4; ++n)
        b[n] = *(const short8*)&Bs[(wn + n * 16 + lrow) * 64 + kk * 32 + lk8];
      #pragma unroll
      for (int m = 0; m < 4; ++m)
        #pragma unroll
        for (int n = 0; n < 4; ++n)
          acc[m][n] = MFMA16(a[m], b[n], acc[m][n]);
    }
  }
  const int g4 = (lane >> 4) << 2;
  #pragma unroll
  for (int n = 0; n < 4; ++n) {
    const int col = col0 + wn + n * 16 + lrow;
    const float bv = bias[col];
    #pragma unroll
    for (int m = 0; m < 4; ++m) {
      const int rbase = row0 + wm + m * 16 + g4;
      #pragma unroll
      for (int r = 0; r < 4; ++r) {
        float v = acc[m][n][r] + bv;
        if (RELU) v = fmaxf(v, 0.f);
        const size_t idx = (size_t)(rbase + r) * N + col;
        if (residual) v += residual[idx];
        if (OUT_BF16) ((unsigned short*)Cout)[idx] = f2bf(v);
        else          ((float*)Cout)[idx] = v;
      }
    }
  }
}

// ---------------- 256x256 8-phase GEMM (T2+T3+T4+T5), C = A @ B^T + bias ----
// 8 waves (2M x 4N), BK=64, LDS 128KB dbuf, XOR-16B-unit swizzle, vmcnt(4).
template <int OUT_BF16, int RELU>
__global__ __launch_bounds__(512, 2) void gemm256(
    const unsigned short* __restrict__ A, int lda,
    const unsigned short* __restrict__ B, int ldb,
    const float* __restrict__ bias,
    const float* __restrict__ residual,
    void* __restrict__ Cout,
    int M, int N, int K, int nbx) {
  __shared__ __align__(16) unsigned short lds[65536];  // A:2x16384 | B:2x16384
  const int NT = K >> 6;
  const int tid = threadIdx.x;
  const int w = tid >> 6, lane = tid & 63;
  const int nwg = gridDim.x, cpx = nwg >> 3;
  const int id = (blockIdx.x & 7) * cpx + (blockIdx.x >> 3);  // XCD swizzle
  const int bx = id % nbx, by = id / nbx;
  const int row0 = by * 256, col0 = bx * 256;
  const int wr128 = (w >> 2) * 128, wc64 = (w & 3) * 64;
  const int lq = lane & 15, g = lane >> 4, g4 = g * 4;
  const int w8 = w * 8;
  const int strow = tid >> 3;                       // 0..63
  const int sw8 = ((tid & 7) ^ (strow & 7)) * 8;    // inverse-swizzled k-offset

  auto stageA = [&](int lr0, int tt, unsigned short* dst) {
    gload_lds16(A + (size_t)(row0 + lr0 + strow) * lda + tt * 64 + sw8,
                dst + (lr0 + w8) * 64);
  };
  auto stageB = [&](int lr0, int tt, unsigned short* dst) {
    gload_lds16(B + (size_t)(col0 + lr0 + strow) * ldb + tt * 64 + sw8,
                dst + (lr0 + w8) * 64);
  };

  f32x4 acc[8][4] = {};

  // prologue: tile 0 (A+B) + tile 1 (B)  [B is staged two tiles ahead]
  {
    unsigned short* A0 = lds;
    unsigned short* B0 = lds + 32768;
    stageA(0, 0, A0); stageA(64, 0, A0); stageA(128, 0, A0); stageA(192, 0, A0);
    stageB(0, 0, B0); stageB(64, 0, B0); stageB(128, 0, B0); stageB(192, 0, B0);
    if (NT > 1) {
      unsigned short* B1 = lds + 32768 + 16384;
      stageB(0, 1, B1); stageB(64, 1, B1); stageB(128, 1, B1); stageB(192, 1, B1);
      asm volatile("s_waitcnt vmcnt(4)" ::: "memory");
    } else {
      asm volatile("s_waitcnt vmcnt(0)" ::: "memory");
    }
    __builtin_amdgcn_s_barrier();
  }

  for (int t = 0; t < NT; ++t) {
    const int buf = t & 1;
    unsigned short* Ab = lds + buf * 16384;
    unsigned short* Bb = lds + 32768 + buf * 16384;
    unsigned short* An = lds + (buf ^ 1) * 16384;   // A dest for tile t+1

    short8 bfr[4][2];
    short8 afr[2][2];

#define LOADA(mbase)                                                          \
    _Pragma("unroll")                                                         \
    for (int i = 0; i < 2; ++i) {                                             \
      const int r_ = wr128 + ((mbase) + i) * 16 + lq;                         \
      afr[i][0] = *(const short8*)(Ab + r_ * 64 + (((g) ^ (r_ & 7)) << 3));   \
      afr[i][1] = *(const short8*)(Ab + r_ * 64 + (((4 + g) ^ (r_ & 7)) << 3));\
    }

#define MFMAQ(p)                                                              \
    _Pragma("unroll")                                                         \
    for (int n = 0; n < 4; ++n) {                                             \
      acc[2*(p)][n]   = MFMA16(afr[0][0], bfr[n][0], acc[2*(p)][n]);          \
      acc[2*(p)][n]   = MFMA16(afr[0][1], bfr[n][1], acc[2*(p)][n]);          \
      acc[2*(p)+1][n] = MFMA16(afr[1][0], bfr[n][0], acc[2*(p)+1][n]);        \
      acc[2*(p)+1][n] = MFMA16(afr[1][1], bfr[n][1], acc[2*(p)+1][n]);        \
    }

    // ---- phase 0: read all B-frags + A m0,m1; stage (t+1, A rows 0,128) ----
    #pragma unroll
    for (int n = 0; n < 4; ++n) {
      const int br = wc64 + n * 16 + lq;
      bfr[n][0] = *(const short8*)(Bb + br * 64 + (((g) ^ (br & 7)) << 3));
      bfr[n][1] = *(const short8*)(Bb + br * 64 + (((4 + g) ^ (br & 7)) << 3));
    }
    LOADA(0);
    if (t + 1 < NT) { stageA(0, t + 1, An); stageA(128, t + 1, An); }
    asm volatile("s_waitcnt lgkmcnt(8)" ::: "memory");
    __builtin_amdgcn_s_barrier();
    asm volatile("s_waitcnt lgkmcnt(0)" ::: "memory");
    __builtin_amdgcn_sched_barrier(0);
    __builtin_amdgcn_s_setprio(1);
    MFMAQ(0);
    __builtin_amdgcn_s_setprio(0);
    __builtin_amdgcn_s_barrier();

    // ---- phase 1: A m2,m3; stage (t+1, A rows 64,192) ----
    LOADA(2);
    if (t + 1 < NT) { stageA(64, t + 1, An); stageA(192, t + 1, An); }
    __builtin_amdgcn_s_barrier();
    asm volatile("s_waitcnt lgkmcnt(0)" ::: "memory");
    __builtin_amdgcn_sched_barrier(0);
    __builtin_amdgcn_s_setprio(1);
    MFMAQ(1);
    __builtin_amdgcn_s_setprio(0);
    __builtin_amdgcn_s_barrier();

    // ---- phase 2: A m4,m5; stage (t+2, B rows 0,64) [B of buf, dead since ph0]
    LOADA(4);
    if (t + 2 < NT) { stageB(0, t + 2, Bb); stageB(64, t + 2, Bb); }
    __builtin_amdgcn_s_barrier();
    asm volatile("s_waitcnt lgkmcnt(0)" ::: "memory");
    __builtin_amdgcn_sched_barrier(0);
    __builtin_amdgcn_s_setprio(1);
    MFMAQ(2);
    __builtin_amdgcn_s_setprio(0);
    __builtin_amdgcn_s_barrier();

    // ---- phase 3: A m6,m7; stage (t+2, B rows 128,192); counted vmcnt ----
    LOADA(6);
    if (t + 2 < NT) { stageB(128, t + 2, Bb); stageB(192, t + 2, Bb); }
    __builtin_amdgcn_s_barrier();
    asm volatile("s_waitcnt lgkmcnt(0)" ::: "memory");
    __builtin_amdgcn_sched_barrier(0);
    __builtin_amdgcn_s_setprio(1);
    MFMAQ(3);
    __builtin_amdgcn_s_setprio(0);
    if (t + 2 < NT) asm volatile("s_waitcnt vmcnt(4)" ::: "memory");
    else            asm volatile("s_waitcnt vmcnt(0)" ::: "memory");
    __builtin_amdgcn_s_barrier();
#undef LOADA
#undef MFMAQ
  }

  // ---- epilogue ----
  #pragma unroll
  for (int n = 0; n < 4; ++n) {
    const int col = col0 + wc64 + n * 16 + lq;
    const float bv = bias[col];
    #pragma unroll
    for (int m = 0; m < 8; ++m) {
      #pragma unroll
      for (int r = 0; r < 4; ++r) {
        const int row = row0 + wr128 + m * 16 + g4 + r;
        float v = acc[m][n][r] + bv;
        if (RELU) v = fmaxf(v, 0.f);
        const size_t idx = (size_t)row * N + col;
        if (residual) v += residual[idx];
        if (OUT_BF16) ((unsigned short*)Cout)[idx] = f2bf(v);
        else          ((float*)Cout)[idx] = v;
      }
    }
  }
}

// ---------------- q [B,S,1024] -> qT [B*H, 64, 1024] (per-head d-major) ------
__global__ __launch_bounds__(256) void transpose_q(
    const unsigned short* __restrict__ q, unsigned short* __restrict__ qT) {
  const int st = blockIdx.x, bh = blockIdx.y;
  const int b = bh >> 4, h = bh & 15;
  __shared__ __align__(16) unsigned short tile[64][80];
  const int tid = threadIdx.x;
  const unsigned short* src = q + ((size_t)(b * 1024 + st * 64)) * 1024 + h * 64;
  #pragma unroll
  for (int j = 0; j < 2; ++j) {
    const int u = tid + j * 256;          // 0..511
    const int sl = u >> 3, d8 = (u & 7) * 8;
    *(short8*)&tile[sl][d8] = *(const short8*)&src[(size_t)sl * 1024 + d8];
  }
  __syncthreads();
  unsigned short* dst = qT + ((size_t)(bh * 64)) * 1024 + st * 64;
  #pragma unroll
  for (int j = 0; j < 2; ++j) {
    const int u = tid + j * 256;
    const int dl = u >> 3, s8 = (u & 7) * 8;
    short8 o;
    #pragma unroll
    for (int i = 0; i < 8; ++i) o[i] = (short)tile[s8 + i][dl];
    *(short8*)&dst[(size_t)dl * 1024 + s8] = o;
  }
}

// ---------------- flash attention v3: LDS-staged K/V, dbuf, 8 waves ----------
__global__ __launch_bounds__(512) void attn_kernel(
    const unsigned short* __restrict__ q,    // [B,S,1024] bf16
    const unsigned short* __restrict__ qT,   // [B*H,64,1024] bf16
    const int* __restrict__ mask,            // [B,1024]
    unsigned short* __restrict__ ctx) {      // [B,S,1024] bf16
  __shared__ __align__(16) unsigned short Ks[2][64 * 64];
  __shared__ __align__(16) unsigned short Vs[2][64 * 64];
  __shared__ __align__(16) unsigned short Pl[8][32 * 64];
  const int id = blockIdx.x;
  const int qt = (id >> 3) & 3;                    // same-bh blocks -> same XCD
  const int bh = (id & 7) * 16 + (id >> 5);
  const int b = bh >> 4, h = bh & 15;
  const int tid = threadIdx.x, w = tid >> 6, lane = tid & 63;
  const int lq = lane & 15;
  const int g = lane >> 4;
  const int lk8 = g * 8;
  const int swz = lane & 7;
  const int q0 = qt * 256 + w * 32;
  const size_t qbase = (size_t)b * (1024 * 1024) + h * 64;
  const size_t qTb = (size_t)bh * 64 * 1024;
  char* Pw = (char*)Pl[w];
  const int srow = lane >> 3;
  const int su = (lane & 7) ^ (srow & 7);
  const size_t ksrc = qbase + (size_t)(w * 8 + srow) * 1024 + su * 8;
  const size_t vsrc = qTb + (size_t)(w * 8 + srow) * 1024 + su * 8;

  short8 qa[2][2];
  #pragma unroll
  for (int qf = 0; qf < 2; ++qf)
    #pragma unroll
    for (int kk = 0; kk < 2; ++kk)
      qa[qf][kk] = *(const short8*)&q[qbase + (size_t)(q0 + qf * 16 + lq) * 1024 + kk * 32 + lk8];

  float mrun[2] = {-1e30f, -1e30f};
  float lrun[2] = {0.f, 0.f};
  f32x4 Oa[2][4];
  #pragma unroll
  for (int mf = 0; mf < 2; ++mf)
    #pragma unroll
    for (int nf = 0; nf < 4; ++nf) Oa[mf][nf] = (f32x4){0.f, 0.f, 0.f, 0.f};

  const int* mrow = mask + b * 1024;

  gload_lds16(q + ksrc, (char*)Ks[0] + w * 1024);
  gload_lds16(qT + vsrc, (char*)Vs[0] + w * 1024);
  asm volatile("s_waitcnt vmcnt(0)" ::: "memory");
  __syncthreads();
  int cur = 0;

  for (int kt = 0; kt < 16; ++kt) {
    const int k0 = kt * 64;
    if (kt < 15) {
      gload_lds16(q + ksrc + (size_t)(k0 + 64) * 1024, (char*)Ks[cur ^ 1] + w * 1024);
      gload_lds16(qT + vsrc + (k0 + 64), (char*)Vs[cur ^ 1] + w * 1024);
    }
    const char* Kb = (const char*)Ks[cur];
    const char* Vb = (const char*)Vs[cur];
    f32x4 s[2][4];
    #pragma unroll
    for (int qf = 0; qf < 2; ++qf)
      #pragma unroll
      for (int kf = 0; kf < 4; ++kf) s[qf][kf] = (f32x4){0.f, 0.f, 0.f, 0.f};
    #pragma unroll
    for (int kf = 0; kf < 4; ++kf) {
      const char* kr = Kb + (kf * 16 + lq) * 128;
      const short8 ka0 = *(const short8*)(kr + (((g) ^ swz) << 4));
      const short8 ka1 = *(const short8*)(kr + (((4 + g) ^ swz) << 4));
      s[0][kf] = MFMA16(ka0, qa[0][0], s[0][kf]);
      s[0][kf] = MFMA16(ka1, qa[0][1], s[0][kf]);
      s[1][kf] = MFMA16(ka0, qa[1][0], s[1][kf]);
      s[1][kf] = MFMA16(ka1, qa[1][1], s[1][kf]);
    }
    float pmax[2] = {-1e30f, -1e30f};
    #pragma unroll
    for (int kf = 0; kf < 4; ++kf) {
      const int4 mv = *(const int4*)&mrow[k0 + kf * 16 + g * 4];
      float madd[4];
      madd[0] = mv.x ? 0.f : -1e9f; madd[1] = mv.y ? 0.f : -1e9f;
      madd[2] = mv.z ? 0.f : -1e9f; madd[3] = mv.w ? 0.f : -1e9f;
      #pragma unroll
      for (int qf = 0; qf < 2; ++qf)
        #pragma unroll
        for (int r = 0; r < 4; ++r) {
          const float v = s[qf][kf][r] * 0.125f + madd[r];
          s[qf][kf][r] = v;
          pmax[qf] = fmaxf(pmax[qf], v);
        }
    }
    #pragma unroll
    for (int qf = 0; qf < 2; ++qf) {
      pmax[qf] = fmaxf(pmax[qf], __shfl_xor(pmax[qf], 16, 64));
      pmax[qf] = fmaxf(pmax[qf], __shfl_xor(pmax[qf], 32, 64));
    }
    const int ok = (pmax[0] <= mrun[0] + 8.f) && (pmax[1] <= mrun[1] + 8.f);
    if (!__all(ok)) {
      float corr[2];
      #pragma unroll
      for (int qf = 0; qf < 2; ++qf) {
        const float mn = fmaxf(mrun[qf], pmax[qf]);
        corr[qf] = __expf(mrun[qf] - mn);
        mrun[qf] = mn;
        lrun[qf] *= corr[qf];
      }
      #pragma unroll
      for (int mf = 0; mf < 2; ++mf)
        #pragma unroll
        for (int r = 0; r < 4; ++r) {
          const float c = __shfl(corr[mf], g * 4 + r, 64);
          #pragma unroll
          for (int nf = 0; nf < 4; ++nf) Oa[mf][nf][r] *= c;
        }
    }
    float tsum[2] = {0.f, 0.f};
    #pragma unroll
    for (int qf = 0; qf < 2; ++qf) {
      const int rowoff = (qf * 16 + lq) * 128;
      #pragma unroll
      for (int kf = 0; kf < 4; ++kf) {
        float p[4];
        #pragma unroll
        for (int r = 0; r < 4; ++r) {
          p[r] = __expf(s[qf][kf][r] - mrun[qf]);
          tsum[qf] += p[r];
        }
        ushort4 pk;
        pk.x = f2bf(p[0]); pk.y = f2bf(p[1]); pk.z = f2bf(p[2]); pk.w = f2bf(p[3]);
        *(ushort4*)(Pw + rowoff + (((2 * kf + (g >> 1)) ^ swz) << 4) + ((g & 1) << 3)) = pk;
      }
    }
    #pragma unroll
    for (int qf = 0; qf < 2; ++qf) {
      tsum[qf] += __shfl_xor(tsum[qf], 16, 64);
      tsum[qf] += __shfl_xor(tsum[qf], 32, 64);
      lrun[qf] += tsum[qf];
    }
    #pragma unroll
    for (int ks = 0; ks < 2; ++ks) {
      short8 pa[2];
      #pragma unroll
      for (int mf = 0; mf < 2; ++mf)
        pa[mf] = *(const short8*)(Pw + (mf * 16 + lq) * 128 + (((4 * ks + g) ^ swz) << 4));
      #pragma unroll
      for (int nf = 0; nf < 4; ++nf) {
        const short8 vb = *(const short8*)(Vb + (nf * 16 + lq) * 128 + (((4 * ks + g) ^ swz) << 4));
        Oa[0][nf] = MFMA16(pa[0], vb, Oa[0][nf]);
        Oa[1][nf] = MFMA16(pa[1], vb, Oa[1][nf]);
      }
    }
    __syncthreads();
    cur ^= 1;
  }
  #pragma unroll
  for (int mf = 0; mf < 2; ++mf) {
    #pragma unroll
    for (int r = 0; r < 4; ++r) {
      const float linv = 1.f / __shfl(lrun[mf], g * 4 + r, 64);
      const int row = q0 + mf * 16 + g * 4 + r;
      #pragma unroll
      for (int nf = 0; nf < 4; ++nf) {
        const int col = h * 64 + nf * 16 + lq;
        ctx[((size_t)b * 1024 + row) * 1024 + col] = f2bf(Oa[mf][nf][r] * linv);
      }
    }
  }
}

// ---------------- launch ----------------------------------------------------
extern "C" void kernel_launch(void* const* d_in, const int* in_sizes, int n_in,
                              void* d_out, int out_size, void* d_ws, size_t ws_size,
                              hipStream_t stream) {
  const float* x    = (const float*)d_in[0];
  const int*   mask = (const int*)d_in[1];
  const float* wq   = (const float*)d_in[2];
  const float* bq   = (const float*)d_in[3];
  const float* wo   = (const float*)d_in[8];
  const float* bo   = (const float*)d_in[9];
  const float* w1   = (const float*)d_in[10];
  const float* b1   = (const float*)d_in[11];
  const float* w2   = (const float*)d_in[12];
  const float* b2   = (const float*)d_in[13];
  const float* ln1a = (const float*)d_in[14];
  const float* ln1b = (const float*)d_in[15];
  const float* ln2a = (const float*)d_in[16];
  const float* ln2b = (const float*)d_in[17];
  float* out = (float*)d_out;

  char* ws = (char*)d_ws;
  unsigned short* wq_b  = (unsigned short*)(ws);                  //  2 MB
  unsigned short* wo_b  = (unsigned short*)(ws + (2l << 20));     //  2 MB
  unsigned short* w1_b  = (unsigned short*)(ws + (4l << 20));     //  8 MB
  unsigned short* w2_b  = (unsigned short*)(ws + (12l << 20));    //  8 MB
  unsigned short* n_b   = (unsigned short*)(ws + (20l << 20));    // 16 MB (n, then n2)
  unsigned short* q_b   = (unsigned short*)(ws + (36l << 20));    // 16 MB
  unsigned short* qT_b  = (unsigned short*)(ws + (52l << 20));    // 16 MB
  unsigned short* ctx_b = (unsigned short*)(ws + (68l << 20));    // 16 MB
  unsigned short* h_b   = (unsigned short*)(ws + (84l << 20));    // 64 MB

  CvtArgs ca{wq, wo, w1, w2, wq_b, wo_b, w1_b, w2_b};
  cvt_weights<<<10240, 256, 0, stream>>>(ca);
  ln_kernel<<<8192, 256, 0, stream>>>(x, ln1a, ln1b, n_b);
  gemm_bt<1, 0><<<dim3(8, 64), 256, 0, stream>>>(n_b, 1024, wq_b, 1024, bq, nullptr, q_b, 8192, 1024, 1024);
  transpose_q<<<dim3(16, 128), 256, 0, stream>>>(q_b, qT_b);
  attn_kernel<<<512, 512, 0, stream>>>(q_b, qT_b, mask, ctx_b);
  gemm_bt<0, 0><<<dim3(8, 64), 256, 0, stream>>>(ctx_b, 1024, wo_b, 1024, bo, x, out, 8192, 1024, 1024);
  ln_kernel<<<8192, 256, 0, stream>>>(out, ln2a, ln2b, n_b);
  gemm256<1, 1><<<512, 512, 0, stream>>>(n_b, 1024, w1_b, 1024, b1, nullptr, h_b, 8192, 4096, 1024, 16);
  gemm256<0, 0><<<128, 512, 0, stream>>>(h_b, 4096, w2_b, 4096, b2, out, out, 8192, 1024, 4096, 4);
}

// Round 5
// 355.244 us; speedup vs baseline: 1.4613x; 1.1461x over previous
//
#include <hip/hip_runtime.h>

typedef __attribute__((ext_vector_type(8))) short short8;
typedef __attribute__((ext_vector_type(4))) float f32x4;

#define MFMA16(a, b, c) __builtin_amdgcn_mfma_f32_16x16x32_bf16((a), (b), (c), 0, 0, 0)

__device__ __forceinline__ unsigned short f2bf(float f) {
  union { float f; unsigned int u; } v; v.f = f;
  return (unsigned short)((v.u + 0x7fffu + ((v.u >> 16) & 1u)) >> 16);
}

__device__ __forceinline__ void gload_lds16(const void* g, void* l) {
  __builtin_amdgcn_global_load_lds((__attribute__((address_space(1))) void*)g,
                                   (__attribute__((address_space(3))) void*)l,
                                   16, 0, 0);
}

// ---------------- weight fp32 -> bf16 conversion (4 arrays in one launch) ----
struct CvtArgs {
  const float* s0; const float* s1; const float* s2; const float* s3;
  unsigned short* d0; unsigned short* d1; unsigned short* d2; unsigned short* d3;
};

__global__ __launch_bounds__(256) void cvt_weights(CvtArgs a) {
  const long N0 = 1048576, N1 = 1048576, N2 = 4194304;  // wq, wo, w1 (w2 rest)
  long i = ((long)blockIdx.x * 256 + threadIdx.x) * 4;
  const float* s; unsigned short* d; long off;
  if (i < N0)                { s = a.s0; d = a.d0; off = i; }
  else if (i < N0 + N1)      { s = a.s1; d = a.d1; off = i - N0; }
  else if (i < N0 + N1 + N2) { s = a.s2; d = a.d2; off = i - N0 - N1; }
  else                       { s = a.s3; d = a.d3; off = i - N0 - N1 - N2; }
  float4 v = *(const float4*)(s + off);
  ushort4 o;
  o.x = f2bf(v.x); o.y = f2bf(v.y); o.z = f2bf(v.z); o.w = f2bf(v.w);
  *(ushort4*)(d + off) = o;
}

// ---------------- LayerNorm (ddof=1, eps added to std), fp32 in -> bf16 out --
__global__ __launch_bounds__(256) void ln_kernel(
    const float* __restrict__ x,
    const float* __restrict__ alpha, const float* __restrict__ beta,
    unsigned short* __restrict__ out) {
  const int row = blockIdx.x;
  const int tid = threadIdx.x;
  const float4 v = ((const float4*)(x + (size_t)row * 1024))[tid];
  float s  = v.x + v.y + v.z + v.w;
  float sq = v.x * v.x + v.y * v.y + v.z * v.z + v.w * v.w;
  #pragma unroll
  for (int d = 32; d >= 1; d >>= 1) {
    s  += __shfl_xor(s, d, 64);
    sq += __shfl_xor(sq, d, 64);
  }
  __shared__ float red[8];
  const int w = tid >> 6;
  if ((tid & 63) == 0) { red[w] = s; red[4 + w] = sq; }
  __syncthreads();
  s  = red[0] + red[1] + red[2] + red[3];
  sq = red[4] + red[5] + red[6] + red[7];
  const float mean = s * (1.f / 1024.f);
  float var = (sq - s * mean) * (1.f / 1023.f);
  var = fmaxf(var, 0.f);
  const float rs = alpha[0] / (sqrtf(var) + 1e-6f);
  const float bb = beta[0];
  ushort4 o;
  o.x = f2bf((v.x - mean) * rs + bb);
  o.y = f2bf((v.y - mean) * rs + bb);
  o.z = f2bf((v.z - mean) * rs + bb);
  o.w = f2bf((v.w - mean) * rs + bb);
  ((ushort4*)out)[(size_t)row * 256 + tid] = o;
}

// ---------------- m97 GEMM (kept for the 1024-col projections) --------------
template <int OUT_BF16, int RELU>
__global__ __launch_bounds__(256) void gemm_bt(
    const unsigned short* __restrict__ A, int lda,
    const unsigned short* __restrict__ B, int ldb,
    const float* __restrict__ bias,
    const float* __restrict__ residual,  // may be null; fp32 [M,N]
    void* __restrict__ Cout,
    int M, int N, int K) {
  __shared__ __align__(16) unsigned short As[128 * 64];
  __shared__ __align__(16) unsigned short Bs[128 * 64];
  const int tid = threadIdx.x;
  const int w = tid >> 6, lane = tid & 63;
  const int row0 = blockIdx.y * 128, col0 = blockIdx.x * 128;
  const int wm = (w >> 1) * 64, wn = (w & 1) * 64;
  const int lrow = lane & 15, lk8 = (lane >> 4) * 8;
  const int srow = lane >> 3, scol = (lane & 7) * 8;
  f32x4 acc[4][4] = {};
  for (int k0 = 0; k0 < K; k0 += 64) {
    __syncthreads();
    #pragma unroll
    for (int i = 0; i < 4; ++i) {
      const int chunk = i * 4 + w;
      const int r = chunk * 8 + srow;
      gload_lds16(A + (size_t)(row0 + r) * lda + k0 + scol, (char*)As + chunk * 1024);
      gload_lds16(B + (size_t)(col0 + r) * ldb + k0 + scol, (char*)Bs + chunk * 1024);
    }
    asm volatile("s_waitcnt vmcnt(0)" ::: "memory");
    __syncthreads();
    #pragma unroll
    for (int kk = 0; kk < 2; ++kk) {
      short8 a[4], b[4];
      #pragma unroll
      for (int m = 0; m < 4; ++m)
        a[m] = *(const short8*)&As[(wm + m * 16 + lrow) * 64 + kk * 32 + lk8];
      #pragma unroll
      for (int n = 0; n < 4; ++n)
        b[n] = *(const short8*)&Bs[(wn + n * 16 + lrow) * 64 + kk * 32 + lk8];
      #pragma unroll
      for (int m = 0; m < 4; ++m)
        #pragma unroll
        for (int n = 0; n < 4; ++n)
          acc[m][n] = MFMA16(a[m], b[n], acc[m][n]);
    }
  }
  const int g4 = (lane >> 4) << 2;
  #pragma unroll
  for (int n = 0; n < 4; ++n) {
    const int col = col0 + wn + n * 16 + lrow;
    const float bv = bias[col];
    #pragma unroll
    for (int m = 0; m < 4; ++m) {
      const int rbase = row0 + wm + m * 16 + g4;
      #pragma unroll
      for (int r = 0; r < 4; ++r) {
        float v = acc[m][n][r] + bv;
        if (RELU) v = fmaxf(v, 0.f);
        const size_t idx = (size_t)(rbase + r) * N + col;
        if (residual) v += residual[idx];
        if (OUT_BF16) ((unsigned short*)Cout)[idx] = f2bf(v);
        else          ((float*)Cout)[idx] = v;
      }
    }
  }
}

// ---------------- 2-phase 256xBN GEMM (T1+T2+T3min), C = A @ B^T + bias -----
// NF = BN/64 n-frags per wave. NF=4 -> BN=256 (waves 2Mx4N, 128x64 each);
// NF=2 -> BN=128 (waves 2Mx4N, 128x32 each). BK=64, dbuf LDS, 1 barrier/tile:
//   stage(next) FIRST -> ds_read+MFMA on cur (compiler lgkm) -> vmcnt(0)+bar.
template <int OUT_BF16, int RELU, int NF>
__global__ __launch_bounds__(512, 2) void gemm2ph(
    const unsigned short* __restrict__ A, int lda,
    const unsigned short* __restrict__ B, int ldb,
    const float* __restrict__ bias,
    const float* __restrict__ residual,
    void* __restrict__ Cout,
    int M, int N, int K, int nbx) {
  __shared__ __align__(16) unsigned short lds[32768 + NF * 8192];
  const int NT = K >> 6;
  const int tid = threadIdx.x;
  const int w = tid >> 6, lane = tid & 63;
  const int cpx = gridDim.x >> 3;
  const int id = (blockIdx.x & 7) * cpx + (blockIdx.x >> 3);  // XCD swizzle
  const int bx = id % nbx, by = id / nbx;
  const int row0 = by * 256, col0 = bx * (NF * 64);
  const int wr128 = (w >> 2) * 128, wcN = (w & 3) * (NF * 16);
  const int lq = lane & 15, g = lane >> 4, g4 = g * 4;
  const int strow = tid >> 3;                        // 0..63
  const int sunit8 = ((tid & 7) ^ (strow & 7)) * 8;  // inverse-swizzled k-off

  const unsigned short* Asrc = A + (size_t)(row0 + strow) * lda + sunit8;
  const unsigned short* Bsrc = B + (size_t)(col0 + strow) * ldb + sunit8;

  auto stage = [&](int buf, int tt) {
    unsigned short* Ad = lds + buf * 16384 + w * 512;
    unsigned short* Bd = lds + 32768 + buf * (NF * 4096) + w * 512;
    #pragma unroll
    for (int c = 0; c < 4; ++c)
      gload_lds16(Asrc + (size_t)(c * 64) * lda + tt * 64, Ad + c * 4096);
    #pragma unroll
    for (int c = 0; c < NF; ++c)
      gload_lds16(Bsrc + (size_t)(c * 64) * ldb + tt * 64, Bd + c * 4096);
  };

  f32x4 acc[8][NF] = {};

  stage(0, 0);
  asm volatile("s_waitcnt vmcnt(0)" ::: "memory");
  __builtin_amdgcn_s_barrier();
  int buf = 0;

  for (int t = 0; t < NT; ++t) {
    if (t + 1 < NT) stage(buf ^ 1, t + 1);
    const unsigned short* Ab = lds + buf * 16384;
    const unsigned short* Bb = lds + 32768 + buf * (NF * 4096);
    #pragma unroll
    for (int kk = 0; kk < 2; ++kk) {
      short8 af[8], bf[NF];
      #pragma unroll
      for (int m = 0; m < 8; ++m) {
        const int r = wr128 + m * 16 + lq;
        af[m] = *(const short8*)(Ab + r * 64 + (((kk * 4 + g) ^ (r & 7)) << 3));
      }
      #pragma unroll
      for (int n = 0; n < NF; ++n) {
        const int r = wcN + n * 16 + lq;
        bf[n] = *(const short8*)(Bb + r * 64 + (((kk * 4 + g) ^ (r & 7)) << 3));
      }
      __builtin_amdgcn_s_setprio(1);
      #pragma unroll
      for (int m = 0; m < 8; ++m)
        #pragma unroll
        for (int n = 0; n < NF; ++n)
          acc[m][n] = MFMA16(af[m], bf[n], acc[m][n]);
      __builtin_amdgcn_s_setprio(0);
    }
    if (t + 1 < NT) {
      asm volatile("s_waitcnt vmcnt(0)" ::: "memory");
      __builtin_amdgcn_s_barrier();
      buf ^= 1;
    }
  }

  // ---- epilogue ----
  #pragma unroll
  for (int n = 0; n < NF; ++n) {
    const int col = col0 + wcN + n * 16 + lq;
    const float bv = bias[col];
    #pragma unroll
    for (int m = 0; m < 8; ++m) {
      #pragma unroll
      for (int r = 0; r < 4; ++r) {
        const int row = row0 + wr128 + m * 16 + g4 + r;
        float v = acc[m][n][r] + bv;
        if (RELU) v = fmaxf(v, 0.f);
        const size_t idx = (size_t)row * N + col;
        if (residual) v += residual[idx];
        if (OUT_BF16) ((unsigned short*)Cout)[idx] = f2bf(v);
        else          ((float*)Cout)[idx] = v;
      }
    }
  }
}

// ---------------- q [B,S,1024] -> qT [B*H, 64, 1024] (per-head d-major) ------
__global__ __launch_bounds__(256) void transpose_q(
    const unsigned short* __restrict__ q, unsigned short* __restrict__ qT) {
  const int st = blockIdx.x, bh = blockIdx.y;
  const int b = bh >> 4, h = bh & 15;
  __shared__ __align__(16) unsigned short tile[64][80];
  const int tid = threadIdx.x;
  const unsigned short* src = q + ((size_t)(b * 1024 + st * 64)) * 1024 + h * 64;
  #pragma unroll
  for (int j = 0; j < 2; ++j) {
    const int u = tid + j * 256;          // 0..511
    const int sl = u >> 3, d8 = (u & 7) * 8;
    *(short8*)&tile[sl][d8] = *(const short8*)&src[(size_t)sl * 1024 + d8];
  }
  __syncthreads();
  unsigned short* dst = qT + ((size_t)(bh * 64)) * 1024 + st * 64;
  #pragma unroll
  for (int j = 0; j < 2; ++j) {
    const int u = tid + j * 256;
    const int dl = u >> 3, s8 = (u & 7) * 8;
    short8 o;
    #pragma unroll
    for (int i = 0; i < 8; ++i) o[i] = (short)tile[s8 + i][dl];
    *(short8*)&dst[(size_t)dl * 1024 + s8] = o;
  }
}

// ---------------- flash attention v3: LDS-staged K/V, dbuf, 8 waves ----------
__global__ __launch_bounds__(512) void attn_kernel(
    const unsigned short* __restrict__ q,    // [B,S,1024] bf16
    const unsigned short* __restrict__ qT,   // [B*H,64,1024] bf16
    const int* __restrict__ mask,            // [B,1024]
    unsigned short* __restrict__ ctx) {      // [B,S,1024] bf16
  __shared__ __align__(16) unsigned short Ks[2][64 * 64];
  __shared__ __align__(16) unsigned short Vs[2][64 * 64];
  __shared__ __align__(16) unsigned short Pl[8][32 * 64];
  const int id = blockIdx.x;
  const int qt = (id >> 3) & 3;                    // same-bh blocks -> same XCD
  const int bh = (id & 7) * 16 + (id >> 5);
  const int b = bh >> 4, h = bh & 15;
  const int tid = threadIdx.x, w = tid >> 6, lane = tid & 63;
  const int lq = lane & 15;
  const int g = lane >> 4;
  const int lk8 = g * 8;
  const int swz = lane & 7;
  const int q0 = qt * 256 + w * 32;
  const size_t qbase = (size_t)b * (1024 * 1024) + h * 64;
  const size_t qTb = (size_t)bh * 64 * 1024;
  char* Pw = (char*)Pl[w];
  const int srow = lane >> 3;
  const int su = (lane & 7) ^ (srow & 7);
  const size_t ksrc = qbase + (size_t)(w * 8 + srow) * 1024 + su * 8;
  const size_t vsrc = qTb + (size_t)(w * 8 + srow) * 1024 + su * 8;

  short8 qa[2][2];
  #pragma unroll
  for (int qf = 0; qf < 2; ++qf)
    #pragma unroll
    for (int kk = 0; kk < 2; ++kk)
      qa[qf][kk] = *(const short8*)&q[qbase + (size_t)(q0 + qf * 16 + lq) * 1024 + kk * 32 + lk8];

  float mrun[2] = {-1e30f, -1e30f};
  float lrun[2] = {0.f, 0.f};
  f32x4 Oa[2][4];
  #pragma unroll
  for (int mf = 0; mf < 2; ++mf)
    #pragma unroll
    for (int nf = 0; nf < 4; ++nf) Oa[mf][nf] = (f32x4){0.f, 0.f, 0.f, 0.f};

  const int* mrow = mask + b * 1024;

  gload_lds16(q + ksrc, (char*)Ks[0] + w * 1024);
  gload_lds16(qT + vsrc, (char*)Vs[0] + w * 1024);
  asm volatile("s_waitcnt vmcnt(0)" ::: "memory");
  __syncthreads();
  int cur = 0;

  for (int kt = 0; kt < 16; ++kt) {
    const int k0 = kt * 64;
    if (kt < 15) {
      gload_lds16(q + ksrc + (size_t)(k0 + 64) * 1024, (char*)Ks[cur ^ 1] + w * 1024);
      gload_lds16(qT + vsrc + (k0 + 64), (char*)Vs[cur ^ 1] + w * 1024);
    }
    const char* Kb = (const char*)Ks[cur];
    const char* Vb = (const char*)Vs[cur];
    f32x4 s[2][4];
    #pragma unroll
    for (int qf = 0; qf < 2; ++qf)
      #pragma unroll
      for (int kf = 0; kf < 4; ++kf) s[qf][kf] = (f32x4){0.f, 0.f, 0.f, 0.f};
    #pragma unroll
    for (int kf = 0; kf < 4; ++kf) {
      const char* kr = Kb + (kf * 16 + lq) * 128;
      const short8 ka0 = *(const short8*)(kr + (((g) ^ swz) << 4));
      const short8 ka1 = *(const short8*)(kr + (((4 + g) ^ swz) << 4));
      s[0][kf] = MFMA16(ka0, qa[0][0], s[0][kf]);
      s[0][kf] = MFMA16(ka1, qa[0][1], s[0][kf]);
      s[1][kf] = MFMA16(ka0, qa[1][0], s[1][kf]);
      s[1][kf] = MFMA16(ka1, qa[1][1], s[1][kf]);
    }
    float pmax[2] = {-1e30f, -1e30f};
    #pragma unroll
    for (int kf = 0; kf < 4; ++kf) {
      const int4 mv = *(const int4*)&mrow[k0 + kf * 16 + g * 4];
      float madd[4];
      madd[0] = mv.x ? 0.f : -1e9f; madd[1] = mv.y ? 0.f : -1e9f;
      madd[2] = mv.z ? 0.f : -1e9f; madd[3] = mv.w ? 0.f : -1e9f;
      #pragma unroll
      for (int qf = 0; qf < 2; ++qf)
        #pragma unroll
        for (int r = 0; r < 4; ++r) {
          const float v = s[qf][kf][r] * 0.125f + madd[r];
          s[qf][kf][r] = v;
          pmax[qf] = fmaxf(pmax[qf], v);
        }
    }
    #pragma unroll
    for (int qf = 0; qf < 2; ++qf) {
      pmax[qf] = fmaxf(pmax[qf], __shfl_xor(pmax[qf], 16, 64));
      pmax[qf] = fmaxf(pmax[qf], __shfl_xor(pmax[qf], 32, 64));
    }
    const int ok = (pmax[0] <= mrun[0] + 8.f) && (pmax[1] <= mrun[1] + 8.f);
    if (!__all(ok)) {
      float corr[2];
      #pragma unroll
      for (int qf = 0; qf < 2; ++qf) {
        const float mn = fmaxf(mrun[qf], pmax[qf]);
        corr[qf] = __expf(mrun[qf] - mn);
        mrun[qf] = mn;
        lrun[qf] *= corr[qf];
      }
      #pragma unroll
      for (int mf = 0; mf < 2; ++mf)
        #pragma unroll
        for (int r = 0; r < 4; ++r) {
          const float c = __shfl(corr[mf], g * 4 + r, 64);
          #pragma unroll
          for (int nf = 0; nf < 4; ++nf) Oa[mf][nf][r] *= c;
        }
    }
    float tsum[2] = {0.f, 0.f};
    #pragma unroll
    for (int qf = 0; qf < 2; ++qf) {
      const int rowoff = (qf * 16 + lq) * 128;
      #pragma unroll
      for (int kf = 0; kf < 4; ++kf) {
        float p[4];
        #pragma unroll
        for (int r = 0; r < 4; ++r) {
          p[r] = __expf(s[qf][kf][r] - mrun[qf]);
          tsum[qf] += p[r];
        }
        ushort4 pk;
        pk.x = f2bf(p[0]); pk.y = f2bf(p[1]); pk.z = f2bf(p[2]); pk.w = f2bf(p[3]);
        *(ushort4*)(Pw + rowoff + (((2 * kf + (g >> 1)) ^ swz) << 4) + ((g & 1) << 3)) = pk;
      }
    }
    #pragma unroll
    for (int qf = 0; qf < 2; ++qf) {
      tsum[qf] += __shfl_xor(tsum[qf], 16, 64);
      tsum[qf] += __shfl_xor(tsum[qf], 32, 64);
      lrun[qf] += tsum[qf];
    }
    #pragma unroll
    for (int ks = 0; ks < 2; ++ks) {
      short8 pa[2];
      #pragma unroll
      for (int mf = 0; mf < 2; ++mf)
        pa[mf] = *(const short8*)(Pw + (mf * 16 + lq) * 128 + (((4 * ks + g) ^ swz) << 4));
      #pragma unroll
      for (int nf = 0; nf < 4; ++nf) {
        const short8 vb = *(const short8*)(Vb + (nf * 16 + lq) * 128 + (((4 * ks + g) ^ swz) << 4));
        Oa[0][nf] = MFMA16(pa[0], vb, Oa[0][nf]);
        Oa[1][nf] = MFMA16(pa[1], vb, Oa[1][nf]);
      }
    }
    __syncthreads();
    cur ^= 1;
  }
  #pragma unroll
  for (int mf = 0; mf < 2; ++mf) {
    #pragma unroll
    for (int r = 0; r < 4; ++r) {
      const float linv = 1.f / __shfl(lrun[mf], g * 4 + r, 64);
      const int row = q0 + mf * 16 + g * 4 + r;
      #pragma unroll
      for (int nf = 0; nf < 4; ++nf) {
        const int col = h * 64 + nf * 16 + lq;
        ctx[((size_t)b * 1024 + row) * 1024 + col] = f2bf(Oa[mf][nf][r] * linv);
      }
    }
  }
}

// ---------------- launch ----------------------------------------------------
extern "C" void kernel_launch(void* const* d_in, const int* in_sizes, int n_in,
                              void* d_out, int out_size, void* d_ws, size_t ws_size,
                              hipStream_t stream) {
  const float* x    = (const float*)d_in[0];
  const int*   mask = (const int*)d_in[1];
  const float* wq   = (const float*)d_in[2];
  const float* bq   = (const float*)d_in[3];
  const float* wo   = (const float*)d_in[8];
  const float* bo   = (const float*)d_in[9];
  const float* w1   = (const float*)d_in[10];
  const float* b1   = (const float*)d_in[11];
  const float* w2   = (const float*)d_in[12];
  const float* b2   = (const float*)d_in[13];
  const float* ln1a = (const float*)d_in[14];
  const float* ln1b = (const float*)d_in[15];
  const float* ln2a = (const float*)d_in[16];
  const float* ln2b = (const float*)d_in[17];
  float* out = (float*)d_out;

  char* ws = (char*)d_ws;
  unsigned short* wq_b  = (unsigned short*)(ws);                  //  2 MB
  unsigned short* wo_b  = (unsigned short*)(ws + (2l << 20));     //  2 MB
  unsigned short* w1_b  = (unsigned short*)(ws + (4l << 20));     //  8 MB
  unsigned short* w2_b  = (unsigned short*)(ws + (12l << 20));    //  8 MB
  unsigned short* n_b   = (unsigned short*)(ws + (20l << 20));    // 16 MB (n, then n2)
  unsigned short* q_b   = (unsigned short*)(ws + (36l << 20));    // 16 MB
  unsigned short* qT_b  = (unsigned short*)(ws + (52l << 20));    // 16 MB
  unsigned short* ctx_b = (unsigned short*)(ws + (68l << 20));    // 16 MB
  unsigned short* h_b   = (unsigned short*)(ws + (84l << 20));    // 64 MB

  CvtArgs ca{wq, wo, w1, w2, wq_b, wo_b, w1_b, w2_b};
  cvt_weights<<<10240, 256, 0, stream>>>(ca);
  ln_kernel<<<8192, 256, 0, stream>>>(x, ln1a, ln1b, n_b);
  gemm_bt<1, 0><<<dim3(8, 64), 256, 0, stream>>>(n_b, 1024, wq_b, 1024, bq, nullptr, q_b, 8192, 1024, 1024);
  transpose_q<<<dim3(16, 128), 256, 0, stream>>>(q_b, qT_b);
  attn_kernel<<<512, 512, 0, stream>>>(q_b, qT_b, mask, ctx_b);
  gemm_bt<0, 0><<<dim3(8, 64), 256, 0, stream>>>(ctx_b, 1024, wo_b, 1024, bo, x, out, 8192, 1024, 1024);
  ln_kernel<<<8192, 256, 0, stream>>>(out, ln2a, ln2b, n_b);
  // FFN1: 256x256 tile, grid 32x16=512; FFN2: 256x128 tile, grid 32x8=256.
  gemm2ph<1, 1, 4><<<512, 512, 0, stream>>>(n_b, 1024, w1_b, 1024, b1, nullptr, h_b, 8192, 4096, 1024, 16);
  gemm2ph<0, 0, 2><<<256, 512, 0, stream>>>(h_b, 4096, w2_b, 4096, b2, out, out, 8192, 1024, 4096, 8);
}